// Round 5
// baseline (3277.494 us; speedup 1.0000x reference)
//
#include <hip/hip_runtime.h>
#include <hip/hip_fp16.h>

#define HID 32
#define R 5
#define BSH 8            // bucket shift: 256 nodes per bucket
#define BCAP 12288       // LDS staging capacity in bucketC (48 KB)

__device__ __forceinline__ float fast_tanh(float x) {
    x = fminf(15.f, fmaxf(-15.f, x));
    float e = __expf(2.f * x);
    return (e - 1.f) / (e + 1.f);
}

// ---------------- CSR build: bucketed 2-level counting sort ----------------

__global__ void zero_kernel(int* p, int n) {
    int i = blockIdx.x * blockDim.x + threadIdx.x;
    if (i < n) p[i] = 0;
}

__global__ void bucketA(const int* __restrict__ dst, int* __restrict__ bucket_cnt,
                        int E, int K) {
    __shared__ int h[512];
    for (int i = threadIdx.x; i < K; i += 256) h[i] = 0;
    __syncthreads();
    int base = blockIdx.x * 4096;
#pragma unroll
    for (int k = 0; k < 16; k++) {
        int e = base + k * 256 + threadIdx.x;
        if (e < E) atomicAdd(&h[dst[e] >> BSH], 1);
    }
    __syncthreads();
    for (int i = threadIdx.x; i < K; i += 256)
        if (h[i]) atomicAdd(&bucket_cnt[i], h[i]);
}

__global__ void scan_buckets(const int* __restrict__ bucket_cnt, int* __restrict__ bucket_base,
                             int* __restrict__ cursor, int K, int E) {
    __shared__ int sh[512];
    int t = threadIdx.x;
    int v = (t < K) ? bucket_cnt[t] : 0;
    sh[t] = v;
    __syncthreads();
    for (int off = 1; off < 512; off <<= 1) {
        int tv = 0;
        if (t >= off) tv = sh[t - off];
        __syncthreads();
        if (t >= off) sh[t] += tv;
        __syncthreads();
    }
    if (t < K) {
        int b = sh[t] - v;
        bucket_base[t] = b;
        cursor[t] = b;
    }
    if (t == 511) bucket_base[K] = sh[511];
}

__global__ void bucketB(const int* __restrict__ src, const int* __restrict__ dst,
                        const int* __restrict__ etype, int* __restrict__ cursor,
                        int* __restrict__ tmp, int E) {
    __shared__ int cnt[512];
    int tid = threadIdx.x;
    for (int i = tid; i < 512; i += 256) cnt[i] = 0;
    __syncthreads();
    int base = blockIdx.x * 4096;
    int lrank[16], pk[16], bk[16];
#pragma unroll
    for (int k = 0; k < 16; k++) {
        int e = base + k * 256 + tid;
        if (e < E) {
            int d = dst[e];
            int b = d >> BSH;
            bk[k] = b;
            pk[k] = src[e] | (etype[e] << 17) | ((d & 255) << 20);
            lrank[k] = atomicAdd(&cnt[b], 1);
        } else {
            bk[k] = -1;
        }
    }
    __syncthreads();
    for (int i = tid; i < 512; i += 256) {
        int c = cnt[i];
        if (c) cnt[i] = atomicAdd(&cursor[i], c);
    }
    __syncthreads();
#pragma unroll
    for (int k = 0; k < 16; k++) {
        if (bk[k] >= 0) tmp[cnt[bk[k]] + lrank[k]] = pk[k];
    }
}

__global__ void bucketC(const int* __restrict__ bucket_base, const int* __restrict__ tmp,
                        int* __restrict__ es, int* __restrict__ row_start,
                        int N, int E, int K) {
    __shared__ int stor[BCAP];
    __shared__ int hist[256];
    __shared__ int sc[256];
    __shared__ int cur[256];
    int b = blockIdx.x;
    int tid = threadIdx.x;
    int beg = bucket_base[b], end = bucket_base[b + 1];
    int cnt = end - beg;
    hist[tid] = 0;
    __syncthreads();
    for (int i = tid; i < cnt; i += 256) {
        int p = tmp[beg + i];
        if (i < BCAP) stor[i] = p;
        atomicAdd(&hist[p >> 20], 1);
    }
    __syncthreads();
    int v = hist[tid];
    sc[tid] = v;
    __syncthreads();
    for (int off = 1; off < 256; off <<= 1) {
        int tv = 0;
        if (tid >= off) tv = sc[tid - off];
        __syncthreads();
        if (tid >= off) sc[tid] += tv;
        __syncthreads();
    }
    int excl = sc[tid] - v;
    int d = (b << BSH) + tid;
    if (d < N) row_start[d] = beg + excl;
    if (b == K - 1 && tid == 0) row_start[N] = E;
    cur[tid] = beg + excl;
    __syncthreads();
    for (int i = tid; i < cnt; i += 256) {
        int p = (i < BCAP) ? stor[i] : tmp[beg + i];
        int ld = p >> 20;
        int pos = atomicAdd(&cur[ld], 1);
        es[pos] = (p & 0x1FFFF) | (((p >> 17) & 7) << 20);
    }
}

// ---------------- per-layer kernels ----------------

// LDS-tiled: 32 nodes/block, W[IN][192] staged once, 8 nodes x 3 cols per thread.
template<int IN>
__global__ void xrsb_kernel(const float* __restrict__ xin, int xstride,
                            const float* __restrict__ bases,  // [2, IN, 32]
                            const float* __restrict__ comp,   // [R, 2]
                            const float* __restrict__ loopw,  // [IN, 32]
                            const float* __restrict__ bias,   // [32]
                            __half* __restrict__ xr, float* __restrict__ selfb, int N) {
    __shared__ float comp_lds[10];
    __shared__ float bias_lds[32];
    __shared__ float Wl[IN * 192];     // [i][j], j: r*32+c for r<5, then loopw cols
    __shared__ float xl[IN][33];       // transposed [k][node], padded
    int tid = threadIdx.x;
    int n0 = blockIdx.x * 32;

    if (tid < 10) comp_lds[tid] = comp[tid];
    if (tid >= 32 && tid < 64) bias_lds[tid - 32] = bias[tid - 32];
    __syncthreads();

    for (int idx = tid; idx < IN * 192; idx += 256) {
        int i = idx / 192, j = idx - i * 192;
        float w;
        if (j < 160) {
            int r = j >> 5, c = j & 31;
            w = fmaf(comp_lds[2 * r], bases[i * HID + c],
                     comp_lds[2 * r + 1] * bases[(IN + i) * HID + c]);
        } else {
            w = loopw[i * HID + (j - 160)];
        }
        Wl[idx] = w;
    }
    constexpr int Q = IN / 4;
    for (int idx = tid; idx < 32 * Q; idx += 256) {
        int m = idx / Q, q = idx - m * Q;
        int n = n0 + m;
        float4 v = make_float4(0.f, 0.f, 0.f, 0.f);
        if (n < N) v = ((const float4*)(xin + (size_t)n * xstride))[q];
        xl[q * 4 + 0][m] = v.x;
        xl[q * 4 + 1][m] = v.y;
        xl[q * 4 + 2][m] = v.z;
        xl[q * 4 + 3][m] = v.w;
    }
    __syncthreads();

    int c0 = tid & 63, ng = tid >> 6;
    int m0 = ng * 8;
    float acc0[8], acc1[8], acc2[8];
#pragma unroll
    for (int m = 0; m < 8; m++) { acc0[m] = 0.f; acc1[m] = 0.f; acc2[m] = 0.f; }
#pragma unroll
    for (int k = 0; k < IN; k++) {
        float w0 = Wl[k * 192 + c0];
        float w1 = Wl[k * 192 + c0 + 64];
        float w2 = Wl[k * 192 + c0 + 128];
#pragma unroll
        for (int m = 0; m < 8; m++) {
            float xv = xl[k][m0 + m];
            acc0[m] = fmaf(xv, w0, acc0[m]);
            acc1[m] = fmaf(xv, w1, acc1[m]);
            acc2[m] = fmaf(xv, w2, acc2[m]);
        }
    }

    int r0 = c0 >> 5, cc0 = c0 & 31;
    int j1 = c0 + 64;
    int r1 = j1 >> 5, cc1 = j1 & 31;
    int j2 = c0 + 128;
    bool j2_self = (j2 >= 160);
    int r2 = j2 >> 5, cc2 = j2_self ? (j2 - 160) : (j2 & 31);
#pragma unroll
    for (int m = 0; m < 8; m++) {
        int n = n0 + m0 + m;
        if (n >= N) break;
        xr[((size_t)r0 * N + n) * HID + cc0] = __float2half(acc0[m]);
        xr[((size_t)r1 * N + n) * HID + cc1] = __float2half(acc1[m]);
        if (j2_self)
            selfb[(size_t)n * HID + cc2] = acc2[m] + bias_lds[cc2];
        else
            xr[((size_t)r2 * N + n) * HID + cc2] = __float2half(acc2[m]);
    }
}

// 8 lanes per dst row, uint2 (4-half) loads, 8 edges in flight -> 64 lines/wave
__global__ void agg_kernel(const int* __restrict__ row_start, const int* __restrict__ es,
                           const __half* __restrict__ xr, const float* __restrict__ selfb,
                           float* __restrict__ C, int col_off, int N) {
    int gid = blockIdx.x * blockDim.x + threadIdx.x;
    int d = gid >> 3;
    if (d >= N) return;
    int c4 = gid & 7;
    int beg = row_start[d], end = row_start[d + 1];
    float a0 = 0.f, a1 = 0.f, a2 = 0.f, a3 = 0.f;
    int i = beg;
    for (; i + 8 <= end; i += 8) {
        int p[8];
#pragma unroll
        for (int k = 0; k < 8; k++) p[k] = es[i + k];
        uint2 v[8];
#pragma unroll
        for (int k = 0; k < 8; k++) {
            size_t row = (size_t)(p[k] >> 20) * N + (p[k] & 0xFFFFF);
            v[k] = ((const uint2*)(xr + row * HID))[c4];
        }
#pragma unroll
        for (int k = 0; k < 8; k++) {
            float2 lo = __half22float2(*reinterpret_cast<__half2*>(&v[k].x));
            float2 hi = __half22float2(*reinterpret_cast<__half2*>(&v[k].y));
            a0 += lo.x; a1 += lo.y; a2 += hi.x; a3 += hi.y;
        }
    }
    for (; i < end; i++) {
        int p = es[i];
        size_t row = (size_t)(p >> 20) * N + (p & 0xFFFFF);
        uint2 vv = ((const uint2*)(xr + row * HID))[c4];
        float2 lo = __half22float2(*reinterpret_cast<__half2*>(&vv.x));
        float2 hi = __half22float2(*reinterpret_cast<__half2*>(&vv.y));
        a0 += lo.x; a1 += lo.y; a2 += hi.x; a3 += hi.y;
    }
    int c = c4 * 4;
    const float4 sb = *(const float4*)(selfb + (size_t)d * HID + c);
    float4 h;
    h.x = fast_tanh(a0 + sb.x);
    h.y = fast_tanh(a1 + sb.y);
    h.z = fast_tanh(a2 + sb.z);
    h.w = fast_tanh(a3 + sb.w);
    *(float4*)(C + (size_t)d * 128 + col_off + c) = h;
}

// ---------------- final MLP ----------------

#define NG 16
__global__ void mlp_kernel(const float* __restrict__ C, const int* __restrict__ uid,
                           const int* __restrict__ vid, const float* __restrict__ w1,
                           const float* __restrict__ bl1, const float* __restrict__ w2,
                           const float* __restrict__ bl2, float* __restrict__ out, int G) {
    __shared__ float f[NG][256];
    __shared__ float red[NG][128];
    int g0 = blockIdx.x * NG;
    int t = threadIdx.x;
    for (int i = t; i < NG * 256; i += 128) {
        int g = i >> 8, k = i & 255;
        int gg = g0 + g;
        float v = 0.f;
        if (gg < G) {
            int node = (k < 128) ? uid[gg] : vid[gg];
            v = C[(size_t)node * 128 + (k & 127)];
        }
        f[g][k] = v;
    }
    __syncthreads();
    float acc[NG];
    float b1v = bl1[t];
#pragma unroll
    for (int g = 0; g < NG; g++) acc[g] = b1v;
    for (int k = 0; k < 256; k++) {
        float wv = w1[k * 128 + t];
#pragma unroll
        for (int g = 0; g < NG; g++) acc[g] = fmaf(f[g][k], wv, acc[g]);
    }
    float w2v = w2[t];
#pragma unroll
    for (int g = 0; g < NG; g++) red[g][t] = fmaxf(acc[g], 0.f) * w2v;
    __syncthreads();
    int g = t >> 3, part = t & 7;
    float s = 0.f;
#pragma unroll
    for (int i = 0; i < 16; i++) s += red[g][part * 16 + i];
    s += __shfl_down(s, 4, 8);
    s += __shfl_down(s, 2, 8);
    s += __shfl_down(s, 1, 8);
    if (part == 0 && g0 + g < G) out[g0 + g] = s + bl2[0];
}

extern "C" void kernel_launch(void* const* d_in, const int* in_sizes, int n_in,
                              void* d_out, int out_size, void* d_ws, size_t ws_size,
                              hipStream_t stream) {
    const float* x   = (const float*)d_in[0];
    const int* src   = (const int*)d_in[1];
    const int* dst   = (const int*)d_in[2];
    const int* etype = (const int*)d_in[3];
    const int* uid   = (const int*)d_in[4];
    const int* vid   = (const int*)d_in[5];
    int N = in_sizes[0] / 4;
    int E = in_sizes[1];
    int G = in_sizes[4];
    int K = (N + 255) >> BSH;

    char* wp = (char*)d_ws;
    auto alloc = [&](size_t bytes) {
        char* p = wp;
        wp += (bytes + 255) & ~(size_t)255;
        return p;
    };
    int* row_start   = (int*)alloc((N + 1) * 4);
    int* bucket_cnt  = (int*)alloc(512 * 4);
    int* bucket_base = (int*)alloc(513 * 4);
    int* cursor      = (int*)alloc(512 * 4);
    int* es          = (int*)alloc((size_t)E * 4);
    __half* xr       = (__half*)alloc((size_t)R * N * HID * 2);
    int* tmp         = (int*)xr;   // aliases xr (consumed by bucketC before xr is written)
    float* selfb     = (float*)alloc((size_t)N * HID * 4);
    float* C         = (float*)alloc((size_t)N * 128 * 4);

    int ebb = (E + 4095) / 4096;
    int xb = (N + 31) / 32;
    int agg_blocks = (N * 8 + 255) / 256;

    // ---- CSR build ----
    zero_kernel<<<2, 256, 0, stream>>>(bucket_cnt, 512);
    bucketA<<<ebb, 256, 0, stream>>>(dst, bucket_cnt, E, K);
    scan_buckets<<<1, 512, 0, stream>>>(bucket_cnt, bucket_base, cursor, K, E);
    bucketB<<<ebb, 256, 0, stream>>>(src, dst, etype, cursor, tmp, E);
    bucketC<<<K, 256, 0, stream>>>(bucket_base, tmp, es, row_start, N, E, K);

    // ---- layers ----
    for (int l = 0; l < 4; l++) {
        const float* bases = (const float*)d_in[6 + l * 4];
        const float* comp  = (const float*)d_in[7 + l * 4];
        const float* loopw = (const float*)d_in[8 + l * 4];
        const float* bias  = (const float*)d_in[9 + l * 4];
        if (l == 0)
            xrsb_kernel<4><<<xb, 256, 0, stream>>>(x, 4, bases, comp, loopw, bias,
                                                   xr, selfb, N);
        else
            xrsb_kernel<32><<<xb, 256, 0, stream>>>(C + (l - 1) * HID, 128, bases, comp,
                                                    loopw, bias, xr, selfb, N);
        agg_kernel<<<agg_blocks, 256, 0, stream>>>(row_start, es, xr, selfb, C, l * HID, N);
    }

    int gblocks = (G + NG - 1) / NG;
    mlp_kernel<<<gblocks, 128, 0, stream>>>(C, uid, vid,
                                            (const float*)d_in[22], (const float*)d_in[23],
                                            (const float*)d_in[24], (const float*)d_in[25],
                                            (float*)d_out, G);
}

// Round 6
// 722.159 us; speedup vs baseline: 4.5385x; 4.5385x over previous
//
#include <hip/hip_runtime.h>
#include <hip/hip_fp16.h>

#define HID 32
#define R 5
#define BSH 8            // bucket shift: 256 nodes per bucket
#define BCAP 12288       // LDS staging capacity in bucketC (48 KB)

__device__ __forceinline__ float fast_tanh(float x) {
    x = fminf(15.f, fmaxf(-15.f, x));
    float e = __expf(2.f * x);
    return (e - 1.f) / (e + 1.f);
}

// ---------------- CSR build: bucketed 2-level counting sort ----------------

__global__ void zero_kernel(int* p, int n) {
    int i = blockIdx.x * blockDim.x + threadIdx.x;
    if (i < n) p[i] = 0;
}

__global__ void bucketA(const int* __restrict__ dst, int* __restrict__ bucket_cnt,
                        int E, int K) {
    __shared__ int h[512];
    for (int i = threadIdx.x; i < K; i += 256) h[i] = 0;
    __syncthreads();
    int base = blockIdx.x * 4096;
#pragma unroll
    for (int k = 0; k < 16; k++) {
        int e = base + k * 256 + threadIdx.x;
        if (e < E) atomicAdd(&h[dst[e] >> BSH], 1);
    }
    __syncthreads();
    for (int i = threadIdx.x; i < K; i += 256)
        if (h[i]) atomicAdd(&bucket_cnt[i], h[i]);
}

__global__ void scan_buckets(const int* __restrict__ bucket_cnt, int* __restrict__ bucket_base,
                             int* __restrict__ cursor, int K, int E) {
    __shared__ int sh[512];
    int t = threadIdx.x;
    int v = (t < K) ? bucket_cnt[t] : 0;
    sh[t] = v;
    __syncthreads();
    for (int off = 1; off < 512; off <<= 1) {
        int tv = 0;
        if (t >= off) tv = sh[t - off];
        __syncthreads();
        if (t >= off) sh[t] += tv;
        __syncthreads();
    }
    if (t < K) {
        int b = sh[t] - v;
        bucket_base[t] = b;
        cursor[t] = b;
    }
    if (t == 511) bucket_base[K] = sh[511];
}

__global__ void bucketB(const int* __restrict__ src, const int* __restrict__ dst,
                        const int* __restrict__ etype, int* __restrict__ cursor,
                        int* __restrict__ tmp, int E) {
    __shared__ int cnt[512];
    int tid = threadIdx.x;
    for (int i = tid; i < 512; i += 256) cnt[i] = 0;
    __syncthreads();
    int base = blockIdx.x * 4096;
    int lrank[16], pk[16], bk[16];
#pragma unroll
    for (int k = 0; k < 16; k++) {
        int e = base + k * 256 + tid;
        if (e < E) {
            int d = dst[e];
            int b = d >> BSH;
            bk[k] = b;
            pk[k] = src[e] | (etype[e] << 17) | ((d & 255) << 20);
            lrank[k] = atomicAdd(&cnt[b], 1);
        } else {
            bk[k] = -1;
        }
    }
    __syncthreads();
    for (int i = tid; i < 512; i += 256) {
        int c = cnt[i];
        if (c) cnt[i] = atomicAdd(&cursor[i], c);
    }
    __syncthreads();
#pragma unroll
    for (int k = 0; k < 16; k++) {
        if (bk[k] >= 0) tmp[cnt[bk[k]] + lrank[k]] = pk[k];
    }
}

__global__ void bucketC(const int* __restrict__ bucket_base, const int* __restrict__ tmp,
                        int* __restrict__ es, int* __restrict__ row_start,
                        int N, int E, int K) {
    __shared__ int stor[BCAP];
    __shared__ int hist[256];
    __shared__ int sc[256];
    __shared__ int cur[256];
    int b = blockIdx.x;
    int tid = threadIdx.x;
    int beg = bucket_base[b], end = bucket_base[b + 1];
    int cnt = end - beg;
    hist[tid] = 0;
    __syncthreads();
    for (int i = tid; i < cnt; i += 256) {
        int p = tmp[beg + i];
        if (i < BCAP) stor[i] = p;
        atomicAdd(&hist[p >> 20], 1);
    }
    __syncthreads();
    int v = hist[tid];
    sc[tid] = v;
    __syncthreads();
    for (int off = 1; off < 256; off <<= 1) {
        int tv = 0;
        if (tid >= off) tv = sc[tid - off];
        __syncthreads();
        if (tid >= off) sc[tid] += tv;
        __syncthreads();
    }
    int excl = sc[tid] - v;
    int d = (b << BSH) + tid;
    if (d < N) row_start[d] = beg + excl;
    if (b == K - 1 && tid == 0) row_start[N] = E;
    cur[tid] = beg + excl;
    __syncthreads();
    for (int i = tid; i < cnt; i += 256) {
        int p = (i < BCAP) ? stor[i] : tmp[beg + i];
        int ld = p >> 20;
        int pos = atomicAdd(&cur[ld], 1);
        es[pos] = (p & 0x1FFFF) | (((p >> 17) & 7) << 20);
    }
}

// ---------------- per-layer kernels ----------------

// LDS-tiled, spill-safe: 64 nodes/block. Thread = (node-group g of 8, col q).
// Outputs j = q + 32*s, s=0..4 -> xr relations, s=5 -> selfb.
template<int IN>
__global__ void __launch_bounds__(256, 2)
xrsb_kernel(const float* __restrict__ xin, int xstride,
            const float* __restrict__ bases,  // [2, IN, 32]
            const float* __restrict__ comp,   // [R, 2]
            const float* __restrict__ loopw,  // [IN, 32]
            const float* __restrict__ bias,   // [32]
            __half* __restrict__ xr, float* __restrict__ selfb, int N) {
    __shared__ float Wt[192 * (IN + 1)];   // transposed [j][k], row stride IN+1
    __shared__ float xt[64 * IN];          // node-major [m][k]
    int tid = threadIdx.x;
    int n0 = blockIdx.x * 64;

    // build combined weight, transposed
    for (int idx = tid; idx < 192 * IN; idx += 256) {
        int j = idx / IN, k = idx - j * IN;
        float w;
        if (j < 160) {
            int r = j >> 5, c = j & 31;
            w = fmaf(comp[2 * r], bases[k * HID + c],
                     comp[2 * r + 1] * bases[(IN + k) * HID + c]);
        } else {
            w = loopw[k * HID + (j - 160)];
        }
        Wt[j * (IN + 1) + k] = w;
    }
    // stage x rows node-major
    constexpr int Q = IN / 4;
    for (int idx = tid; idx < 64 * Q; idx += 256) {
        int m = idx / Q, kq = idx - m * Q;
        int n = n0 + m;
        float4 v = make_float4(0.f, 0.f, 0.f, 0.f);
        if (n < N) v = ((const float4*)(xin + (size_t)n * xstride))[kq];
        *(float4*)&xt[m * IN + kq * 4] = v;
    }
    __syncthreads();

    int q = tid & 31, g = tid >> 5;
    int m0 = g * 8;
    float acc[6][8];
#pragma unroll
    for (int s = 0; s < 6; s++)
#pragma unroll
        for (int m = 0; m < 8; m++) acc[s][m] = 0.f;

    for (int k4 = 0; k4 < IN; k4 += 4) {
        float4 xv[8];
#pragma unroll
        for (int m = 0; m < 8; m++)
            xv[m] = *(const float4*)&xt[(m0 + m) * IN + k4];
#pragma unroll
        for (int kk = 0; kk < 4; kk++) {
            float w[6];
#pragma unroll
            for (int s = 0; s < 6; s++)
                w[s] = Wt[(q + 32 * s) * (IN + 1) + k4 + kk];
#pragma unroll
            for (int m = 0; m < 8; m++) {
                float xk = (&xv[m].x)[kk];
#pragma unroll
                for (int s = 0; s < 6; s++)
                    acc[s][m] = fmaf(xk, w[s], acc[s][m]);
            }
        }
    }

    float bq = bias[q];
#pragma unroll
    for (int m = 0; m < 8; m++) {
        int n = n0 + m0 + m;
        if (n >= N) break;
#pragma unroll
        for (int s = 0; s < 5; s++)
            xr[((size_t)s * N + n) * HID + q] = __float2half(acc[s][m]);
        selfb[(size_t)n * HID + q] = acc[5][m] + bq;
    }
}

// 8 lanes per dst row, uint2 (4-half) loads, 8 edges in flight -> 64 lines/wave
__global__ void agg_kernel(const int* __restrict__ row_start, const int* __restrict__ es,
                           const __half* __restrict__ xr, const float* __restrict__ selfb,
                           float* __restrict__ C, int col_off, int N) {
    int gid = blockIdx.x * blockDim.x + threadIdx.x;
    int d = gid >> 3;
    if (d >= N) return;
    int c4 = gid & 7;
    int beg = row_start[d], end = row_start[d + 1];
    float a0 = 0.f, a1 = 0.f, a2 = 0.f, a3 = 0.f;
    int i = beg;
    for (; i + 8 <= end; i += 8) {
        int p[8];
#pragma unroll
        for (int k = 0; k < 8; k++) p[k] = es[i + k];
        uint2 v[8];
#pragma unroll
        for (int k = 0; k < 8; k++) {
            size_t row = (size_t)(p[k] >> 20) * N + (p[k] & 0xFFFFF);
            v[k] = ((const uint2*)(xr + row * HID))[c4];
        }
#pragma unroll
        for (int k = 0; k < 8; k++) {
            float2 lo = __half22float2(*reinterpret_cast<__half2*>(&v[k].x));
            float2 hi = __half22float2(*reinterpret_cast<__half2*>(&v[k].y));
            a0 += lo.x; a1 += lo.y; a2 += hi.x; a3 += hi.y;
        }
    }
    for (; i < end; i++) {
        int p = es[i];
        size_t row = (size_t)(p >> 20) * N + (p & 0xFFFFF);
        uint2 vv = ((const uint2*)(xr + row * HID))[c4];
        float2 lo = __half22float2(*reinterpret_cast<__half2*>(&vv.x));
        float2 hi = __half22float2(*reinterpret_cast<__half2*>(&vv.y));
        a0 += lo.x; a1 += lo.y; a2 += hi.x; a3 += hi.y;
    }
    int c = c4 * 4;
    const float4 sb = *(const float4*)(selfb + (size_t)d * HID + c);
    float4 h;
    h.x = fast_tanh(a0 + sb.x);
    h.y = fast_tanh(a1 + sb.y);
    h.z = fast_tanh(a2 + sb.z);
    h.w = fast_tanh(a3 + sb.w);
    *(float4*)(C + (size_t)d * 128 + col_off + c) = h;
}

// ---------------- final MLP ----------------

#define NG 16
__global__ void mlp_kernel(const float* __restrict__ C, const int* __restrict__ uid,
                           const int* __restrict__ vid, const float* __restrict__ w1,
                           const float* __restrict__ bl1, const float* __restrict__ w2,
                           const float* __restrict__ bl2, float* __restrict__ out, int G) {
    __shared__ float f[NG][256];
    __shared__ float red[NG][128];
    int g0 = blockIdx.x * NG;
    int t = threadIdx.x;
    for (int i = t; i < NG * 256; i += 128) {
        int g = i >> 8, k = i & 255;
        int gg = g0 + g;
        float v = 0.f;
        if (gg < G) {
            int node = (k < 128) ? uid[gg] : vid[gg];
            v = C[(size_t)node * 128 + (k & 127)];
        }
        f[g][k] = v;
    }
    __syncthreads();
    float acc[NG];
    float b1v = bl1[t];
#pragma unroll
    for (int g = 0; g < NG; g++) acc[g] = b1v;
    for (int k = 0; k < 256; k++) {
        float wv = w1[k * 128 + t];
#pragma unroll
        for (int g = 0; g < NG; g++) acc[g] = fmaf(f[g][k], wv, acc[g]);
    }
    float w2v = w2[t];
#pragma unroll
    for (int g = 0; g < NG; g++) red[g][t] = fmaxf(acc[g], 0.f) * w2v;
    __syncthreads();
    int g = t >> 3, part = t & 7;
    float s = 0.f;
#pragma unroll
    for (int i = 0; i < 16; i++) s += red[g][part * 16 + i];
    s += __shfl_down(s, 4, 8);
    s += __shfl_down(s, 2, 8);
    s += __shfl_down(s, 1, 8);
    if (part == 0 && g0 + g < G) out[g0 + g] = s + bl2[0];
}

extern "C" void kernel_launch(void* const* d_in, const int* in_sizes, int n_in,
                              void* d_out, int out_size, void* d_ws, size_t ws_size,
                              hipStream_t stream) {
    const float* x   = (const float*)d_in[0];
    const int* src   = (const int*)d_in[1];
    const int* dst   = (const int*)d_in[2];
    const int* etype = (const int*)d_in[3];
    const int* uid   = (const int*)d_in[4];
    const int* vid   = (const int*)d_in[5];
    int N = in_sizes[0] / 4;
    int E = in_sizes[1];
    int G = in_sizes[4];
    int K = (N + 255) >> BSH;

    char* wp = (char*)d_ws;
    auto alloc = [&](size_t bytes) {
        char* p = wp;
        wp += (bytes + 255) & ~(size_t)255;
        return p;
    };
    int* row_start   = (int*)alloc((N + 1) * 4);
    int* bucket_cnt  = (int*)alloc(512 * 4);
    int* bucket_base = (int*)alloc(513 * 4);
    int* cursor      = (int*)alloc(512 * 4);
    int* es          = (int*)alloc((size_t)E * 4);
    __half* xr       = (__half*)alloc((size_t)R * N * HID * 2);
    int* tmp         = (int*)xr;   // aliases xr (consumed by bucketC before xr is written)
    float* selfb     = (float*)alloc((size_t)N * HID * 4);
    float* C         = (float*)alloc((size_t)N * 128 * 4);

    int ebb = (E + 4095) / 4096;
    int xb = (N + 63) / 64;
    int agg_blocks = (N * 8 + 255) / 256;

    // ---- CSR build ----
    zero_kernel<<<2, 256, 0, stream>>>(bucket_cnt, 512);
    bucketA<<<ebb, 256, 0, stream>>>(dst, bucket_cnt, E, K);
    scan_buckets<<<1, 512, 0, stream>>>(bucket_cnt, bucket_base, cursor, K, E);
    bucketB<<<ebb, 256, 0, stream>>>(src, dst, etype, cursor, tmp, E);
    bucketC<<<K, 256, 0, stream>>>(bucket_base, tmp, es, row_start, N, E, K);

    // ---- layers ----
    for (int l = 0; l < 4; l++) {
        const float* bases = (const float*)d_in[6 + l * 4];
        const float* comp  = (const float*)d_in[7 + l * 4];
        const float* loopw = (const float*)d_in[8 + l * 4];
        const float* bias  = (const float*)d_in[9 + l * 4];
        if (l == 0)
            xrsb_kernel<4><<<xb, 256, 0, stream>>>(x, 4, bases, comp, loopw, bias,
                                                   xr, selfb, N);
        else
            xrsb_kernel<32><<<xb, 256, 0, stream>>>(C + (l - 1) * HID, 128, bases, comp,
                                                    loopw, bias, xr, selfb, N);
        agg_kernel<<<agg_blocks, 256, 0, stream>>>(row_start, es, xr, selfb, C, l * HID, N);
    }

    int gblocks = (G + NG - 1) / NG;
    mlp_kernel<<<gblocks, 128, 0, stream>>>(C, uid, vid,
                                            (const float*)d_in[22], (const float*)d_in[23],
                                            (const float*)d_in[24], (const float*)d_in[25],
                                            (float*)d_out, G);
}

// Round 7
// 681.650 us; speedup vs baseline: 4.8082x; 1.0594x over previous
//
#include <hip/hip_runtime.h>
#include <hip/hip_fp16.h>

#define HID 32
#define R 5
#define BSH 8            // bucket shift: 256 nodes per bucket
#define BCAP 12288       // LDS staging capacity in bucketC (48 KB)

__device__ __forceinline__ float fast_tanh(float x) {
    x = fminf(15.f, fmaxf(-15.f, x));
    float e = __expf(2.f * x);
    return (e - 1.f) / (e + 1.f);
}

// ---------------- CSR build: bucketed 2-level counting sort ----------------

__global__ void zero_kernel(int* p, int n) {
    int i = blockIdx.x * blockDim.x + threadIdx.x;
    if (i < n) p[i] = 0;
}

__global__ void bucketA(const int* __restrict__ dst, int* __restrict__ bucket_cnt,
                        int E, int K) {
    __shared__ int h[512];
    for (int i = threadIdx.x; i < K; i += 256) h[i] = 0;
    __syncthreads();
    int base = blockIdx.x * 4096;
#pragma unroll
    for (int k = 0; k < 16; k++) {
        int e = base + k * 256 + threadIdx.x;
        if (e < E) atomicAdd(&h[dst[e] >> BSH], 1);
    }
    __syncthreads();
    for (int i = threadIdx.x; i < K; i += 256)
        if (h[i]) atomicAdd(&bucket_cnt[i], h[i]);
}

__global__ void scan_buckets(const int* __restrict__ bucket_cnt, int* __restrict__ bucket_base,
                             int* __restrict__ cursor, int K, int E) {
    __shared__ int sh[512];
    int t = threadIdx.x;
    int v = (t < K) ? bucket_cnt[t] : 0;
    sh[t] = v;
    __syncthreads();
    for (int off = 1; off < 512; off <<= 1) {
        int tv = 0;
        if (t >= off) tv = sh[t - off];
        __syncthreads();
        if (t >= off) sh[t] += tv;
        __syncthreads();
    }
    if (t < K) {
        int b = sh[t] - v;
        bucket_base[t] = b;
        cursor[t] = b;
    }
    if (t == 511) bucket_base[K] = sh[511];
}

__global__ void bucketB(const int* __restrict__ src, const int* __restrict__ dst,
                        const int* __restrict__ etype, int* __restrict__ cursor,
                        int* __restrict__ tmp, int E) {
    __shared__ int cnt[512];
    int tid = threadIdx.x;
    for (int i = tid; i < 512; i += 256) cnt[i] = 0;
    __syncthreads();
    int base = blockIdx.x * 4096;
    int lrank[16], pk[16], bk[16];
#pragma unroll
    for (int k = 0; k < 16; k++) {
        int e = base + k * 256 + tid;
        if (e < E) {
            int d = dst[e];
            int b = d >> BSH;
            bk[k] = b;
            pk[k] = src[e] | (etype[e] << 17) | ((d & 255) << 20);
            lrank[k] = atomicAdd(&cnt[b], 1);
        } else {
            bk[k] = -1;
        }
    }
    __syncthreads();
    for (int i = tid; i < 512; i += 256) {
        int c = cnt[i];
        if (c) cnt[i] = atomicAdd(&cursor[i], c);
    }
    __syncthreads();
#pragma unroll
    for (int k = 0; k < 16; k++) {
        if (bk[k] >= 0) tmp[cnt[bk[k]] + lrank[k]] = pk[k];
    }
}

__global__ void bucketC(const int* __restrict__ bucket_base, const int* __restrict__ tmp,
                        int* __restrict__ es, int* __restrict__ row_start,
                        int N, int E, int K) {
    __shared__ int stor[BCAP];
    __shared__ int hist[256];
    __shared__ int sc[256];
    __shared__ int cur[256];
    int b = blockIdx.x;
    int tid = threadIdx.x;
    int beg = bucket_base[b], end = bucket_base[b + 1];
    int cnt = end - beg;
    hist[tid] = 0;
    __syncthreads();
    for (int i = tid; i < cnt; i += 256) {
        int p = tmp[beg + i];
        if (i < BCAP) stor[i] = p;
        atomicAdd(&hist[p >> 20], 1);
    }
    __syncthreads();
    int v = hist[tid];
    sc[tid] = v;
    __syncthreads();
    for (int off = 1; off < 256; off <<= 1) {
        int tv = 0;
        if (tid >= off) tv = sc[tid - off];
        __syncthreads();
        if (tid >= off) sc[tid] += tv;
        __syncthreads();
    }
    int excl = sc[tid] - v;
    int d = (b << BSH) + tid;
    if (d < N) row_start[d] = beg + excl;
    if (b == K - 1 && tid == 0) row_start[N] = E;
    cur[tid] = beg + excl;
    __syncthreads();
    for (int i = tid; i < cnt; i += 256) {
        int p = (i < BCAP) ? stor[i] : tmp[beg + i];
        int ld = p >> 20;
        int pos = atomicAdd(&cur[ld], 1);
        es[pos] = (p & 0x1FFFF) | (((p >> 17) & 7) << 20);
    }
}

// ---------------- per-layer kernels ----------------

// LDS-tiled, spill-safe: 64 nodes/block. Thread = (node-group g of 8, col q).
// Outputs j = q + 32*s, s=0..4 -> xr relations, s=5 -> selfb.
template<int IN>
__global__ void __launch_bounds__(256, 2)
xrsb_kernel(const float* __restrict__ xin, int xstride,
            const float* __restrict__ bases,  // [2, IN, 32]
            const float* __restrict__ comp,   // [R, 2]
            const float* __restrict__ loopw,  // [IN, 32]
            const float* __restrict__ bias,   // [32]
            __half* __restrict__ xr, float* __restrict__ selfb, int N) {
    __shared__ float Wt[192 * (IN + 1)];   // transposed [j][k], row stride IN+1
    __shared__ float xt[64 * IN];          // node-major [m][k]
    int tid = threadIdx.x;
    int n0 = blockIdx.x * 64;

    for (int idx = tid; idx < 192 * IN; idx += 256) {
        int j = idx / IN, k = idx - j * IN;
        float w;
        if (j < 160) {
            int r = j >> 5, c = j & 31;
            w = fmaf(comp[2 * r], bases[k * HID + c],
                     comp[2 * r + 1] * bases[(IN + k) * HID + c]);
        } else {
            w = loopw[k * HID + (j - 160)];
        }
        Wt[j * (IN + 1) + k] = w;
    }
    constexpr int Q = IN / 4;
    for (int idx = tid; idx < 64 * Q; idx += 256) {
        int m = idx / Q, kq = idx - m * Q;
        int n = n0 + m;
        float4 v = make_float4(0.f, 0.f, 0.f, 0.f);
        if (n < N) v = ((const float4*)(xin + (size_t)n * xstride))[kq];
        *(float4*)&xt[m * IN + kq * 4] = v;
    }
    __syncthreads();

    int q = tid & 31, g = tid >> 5;
    int m0 = g * 8;
    float acc[6][8];
#pragma unroll
    for (int s = 0; s < 6; s++)
#pragma unroll
        for (int m = 0; m < 8; m++) acc[s][m] = 0.f;

    for (int k4 = 0; k4 < IN; k4 += 4) {
        float4 xv[8];
#pragma unroll
        for (int m = 0; m < 8; m++)
            xv[m] = *(const float4*)&xt[(m0 + m) * IN + k4];
#pragma unroll
        for (int kk = 0; kk < 4; kk++) {
            float w[6];
#pragma unroll
            for (int s = 0; s < 6; s++)
                w[s] = Wt[(q + 32 * s) * (IN + 1) + k4 + kk];
#pragma unroll
            for (int m = 0; m < 8; m++) {
                float xk = (&xv[m].x)[kk];
#pragma unroll
                for (int s = 0; s < 6; s++)
                    acc[s][m] = fmaf(xk, w[s], acc[s][m]);
            }
        }
    }

    float bq = bias[q];
#pragma unroll
    for (int m = 0; m < 8; m++) {
        int n = n0 + m0 + m;
        if (n >= N) break;
#pragma unroll
        for (int s = 0; s < 5; s++)
            xr[((size_t)s * N + n) * HID + q] = __float2half(acc[s][m]);
        selfb[(size_t)n * HID + q] = acc[5][m] + bq;
    }
}

// 8 lanes per dst row, uint2 (4-half) loads, 8 edges in flight -> 64 lines/wave
__global__ void agg_kernel(const int* __restrict__ row_start, const int* __restrict__ es,
                           const __half* __restrict__ xr, const float* __restrict__ selfb,
                           float* __restrict__ C, int col_off, int N) {
    int gid = blockIdx.x * blockDim.x + threadIdx.x;
    int d = gid >> 3;
    if (d >= N) return;
    int c4 = gid & 7;
    int beg = row_start[d], end = row_start[d + 1];
    float a0 = 0.f, a1 = 0.f, a2 = 0.f, a3 = 0.f;
    int i = beg;
    for (; i + 8 <= end; i += 8) {
        int p[8];
#pragma unroll
        for (int k = 0; k < 8; k++) p[k] = es[i + k];
        uint2 v[8];
#pragma unroll
        for (int k = 0; k < 8; k++) {
            size_t row = (size_t)(p[k] >> 20) * N + (p[k] & 0xFFFFF);
            v[k] = ((const uint2*)(xr + row * HID))[c4];
        }
#pragma unroll
        for (int k = 0; k < 8; k++) {
            float2 lo = __half22float2(*reinterpret_cast<__half2*>(&v[k].x));
            float2 hi = __half22float2(*reinterpret_cast<__half2*>(&v[k].y));
            a0 += lo.x; a1 += lo.y; a2 += hi.x; a3 += hi.y;
        }
    }
    for (; i < end; i++) {
        int p = es[i];
        size_t row = (size_t)(p >> 20) * N + (p & 0xFFFFF);
        uint2 vv = ((const uint2*)(xr + row * HID))[c4];
        float2 lo = __half22float2(*reinterpret_cast<__half2*>(&vv.x));
        float2 hi = __half22float2(*reinterpret_cast<__half2*>(&vv.y));
        a0 += lo.x; a1 += lo.y; a2 += hi.x; a3 += hi.y;
    }
    int c = c4 * 4;
    const float4 sb = *(const float4*)(selfb + (size_t)d * HID + c);
    float4 h;
    h.x = fast_tanh(a0 + sb.x);
    h.y = fast_tanh(a1 + sb.y);
    h.z = fast_tanh(a2 + sb.z);
    h.w = fast_tanh(a3 + sb.w);
    *(float4*)(C + (size_t)d * 128 + col_off + c) = h;
}

// ---------------- final MLP ----------------
// 16 pairs/block, 256 threads. Thread = (q32 in [0,32), gs in [0,4), h in [0,2)).
// Each thread: 4 neurons (q32*4..+3) x 4 pairs (gs*4..+3), k-half h.
#define MP 16
__global__ void __launch_bounds__(256, 4)
mlp_kernel(const float* __restrict__ C, const int* __restrict__ uid,
           const int* __restrict__ vid, const float* __restrict__ w1,
           const float* __restrict__ bl1, const float* __restrict__ w2,
           const float* __restrict__ bl2, float* __restrict__ out, int G) {
    __shared__ float feat[MP][2][128];   // [pair][half][k]
    __shared__ float psum[MP][128];
    int g0 = blockIdx.x * MP;
    int tid = threadIdx.x;

    // stage features: MP*2*32 float4s, 4 per thread
    for (int idx = tid; idx < MP * 64; idx += 256) {
        int g = idx >> 6;
        int rem = idx & 63;
        int which = rem >> 5;
        int q4 = rem & 31;
        int gg = g0 + g;
        float4 v = make_float4(0.f, 0.f, 0.f, 0.f);
        if (gg < G) {
            int node = which ? vid[gg] : uid[gg];
            v = ((const float4*)(C + (size_t)node * 128))[q4];
        }
        *(float4*)&feat[g][which][q4 * 4] = v;
    }
    __syncthreads();

    int q32 = tid & 31;
    int gs = (tid >> 5) & 3;
    int h = tid >> 7;
    float acc[4][4];   // [pair j][neuron i]
#pragma unroll
    for (int j = 0; j < 4; j++)
#pragma unroll
        for (int i = 0; i < 4; i++) acc[j][i] = 0.f;

    const float* wbase = w1 + (size_t)(h * 128) * 128 + q32 * 4;
    for (int k = 0; k < 128; k++) {
        float4 wv = *(const float4*)(wbase + (size_t)k * 128);
        float fv[4];
#pragma unroll
        for (int j = 0; j < 4; j++) fv[j] = feat[gs * 4 + j][h][k];
#pragma unroll
        for (int j = 0; j < 4; j++) {
            acc[j][0] = fmaf(fv[j], wv.x, acc[j][0]);
            acc[j][1] = fmaf(fv[j], wv.y, acc[j][1]);
            acc[j][2] = fmaf(fv[j], wv.z, acc[j][2]);
            acc[j][3] = fmaf(fv[j], wv.w, acc[j][3]);
        }
    }

    // h=1 deposits partial, then h=0 combines + relu + w2 scale
    if (h == 1) {
#pragma unroll
        for (int j = 0; j < 4; j++)
#pragma unroll
            for (int i = 0; i < 4; i++)
                psum[gs * 4 + j][q32 * 4 + i] = acc[j][i];
    }
    __syncthreads();
    if (h == 0) {
#pragma unroll
        for (int j = 0; j < 4; j++) {
#pragma unroll
            for (int i = 0; i < 4; i++) {
                int q = q32 * 4 + i;
                float t = acc[j][i] + psum[gs * 4 + j][q] + bl1[q];
                psum[gs * 4 + j][q] = fmaxf(t, 0.f) * w2[q];
            }
        }
    }
    __syncthreads();

    // reduce 128 values per pair: 8 pair-groups of 32 lanes, 2 passes
    float b2 = bl2[0];
#pragma unroll
    for (int pass = 0; pass < 2; pass++) {
        int g = (tid >> 5) + pass * 8;
        int l = tid & 31;
        float s = psum[g][l] + psum[g][l + 32] + psum[g][l + 64] + psum[g][l + 96];
        s += __shfl_down(s, 16, 32);
        s += __shfl_down(s, 8, 32);
        s += __shfl_down(s, 4, 32);
        s += __shfl_down(s, 2, 32);
        s += __shfl_down(s, 1, 32);
        if (l == 0 && g0 + g < G) out[g0 + g] = s + b2;
    }
}

extern "C" void kernel_launch(void* const* d_in, const int* in_sizes, int n_in,
                              void* d_out, int out_size, void* d_ws, size_t ws_size,
                              hipStream_t stream) {
    const float* x   = (const float*)d_in[0];
    const int* src   = (const int*)d_in[1];
    const int* dst   = (const int*)d_in[2];
    const int* etype = (const int*)d_in[3];
    const int* uid   = (const int*)d_in[4];
    const int* vid   = (const int*)d_in[5];
    int N = in_sizes[0] / 4;
    int E = in_sizes[1];
    int G = in_sizes[4];
    int K = (N + 255) >> BSH;

    char* wp = (char*)d_ws;
    auto alloc = [&](size_t bytes) {
        char* p = wp;
        wp += (bytes + 255) & ~(size_t)255;
        return p;
    };
    int* row_start   = (int*)alloc((N + 1) * 4);
    int* bucket_cnt  = (int*)alloc(512 * 4);
    int* bucket_base = (int*)alloc(513 * 4);
    int* cursor      = (int*)alloc(512 * 4);
    int* es          = (int*)alloc((size_t)E * 4);
    __half* xr       = (__half*)alloc((size_t)R * N * HID * 2);
    int* tmp         = (int*)xr;   // aliases xr (consumed by bucketC before xr is written)
    float* selfb     = (float*)alloc((size_t)N * HID * 4);
    float* C         = (float*)alloc((size_t)N * 128 * 4);

    int ebb = (E + 4095) / 4096;
    int xb = (N + 63) / 64;
    int agg_blocks = (N * 8 + 255) / 256;

    // ---- CSR build ----
    zero_kernel<<<2, 256, 0, stream>>>(bucket_cnt, 512);
    bucketA<<<ebb, 256, 0, stream>>>(dst, bucket_cnt, E, K);
    scan_buckets<<<1, 512, 0, stream>>>(bucket_cnt, bucket_base, cursor, K, E);
    bucketB<<<ebb, 256, 0, stream>>>(src, dst, etype, cursor, tmp, E);
    bucketC<<<K, 256, 0, stream>>>(bucket_base, tmp, es, row_start, N, E, K);

    // ---- layers ----
    for (int l = 0; l < 4; l++) {
        const float* bases = (const float*)d_in[6 + l * 4];
        const float* comp  = (const float*)d_in[7 + l * 4];
        const float* loopw = (const float*)d_in[8 + l * 4];
        const float* bias  = (const float*)d_in[9 + l * 4];
        if (l == 0)
            xrsb_kernel<4><<<xb, 256, 0, stream>>>(x, 4, bases, comp, loopw, bias,
                                                   xr, selfb, N);
        else
            xrsb_kernel<32><<<xb, 256, 0, stream>>>(C + (l - 1) * HID, 128, bases, comp,
                                                    loopw, bias, xr, selfb, N);
        agg_kernel<<<agg_blocks, 256, 0, stream>>>(row_start, es, xr, selfb, C, l * HID, N);
    }

    int gblocks = (G + MP - 1) / MP;
    mlp_kernel<<<gblocks, 256, 0, stream>>>(C, uid, vid,
                                            (const float*)d_in[22], (const float*)d_in[23],
                                            (const float*)d_in[24], (const float*)d_in[25],
                                            (float*)d_out, G);
}

// Round 8
// 677.411 us; speedup vs baseline: 4.8383x; 1.0063x over previous
//
#include <hip/hip_runtime.h>
#include <hip/hip_fp16.h>

#define HID 32
#define R 5
#define BSH 8            // bucket shift: 256 nodes per bucket
#define BCAP 12288       // LDS staging capacity in bucketC (48 KB)

__device__ __forceinline__ float fast_tanh(float x) {
    x = fminf(15.f, fmaxf(-15.f, x));
    float e = __expf(2.f * x);
    return (e - 1.f) / (e + 1.f);
}

// ---------------- CSR build: bucketed 2-level counting sort ----------------

__global__ void bucketA(const int* __restrict__ dst, int* __restrict__ bucket_cnt,
                        int E, int K) {
    __shared__ int h[512];
    for (int i = threadIdx.x; i < K; i += 256) h[i] = 0;
    __syncthreads();
    int base = blockIdx.x * 4096;
#pragma unroll
    for (int k = 0; k < 16; k++) {
        int e = base + k * 256 + threadIdx.x;
        if (e < E) atomicAdd(&h[dst[e] >> BSH], 1);
    }
    __syncthreads();
    for (int i = threadIdx.x; i < K; i += 256)
        if (h[i]) atomicAdd(&bucket_cnt[i], h[i]);
}

__global__ void scan_buckets(const int* __restrict__ bucket_cnt, int* __restrict__ bucket_base,
                             int* __restrict__ cursor, int K, int E) {
    __shared__ int sh[512];
    int t = threadIdx.x;
    int v = (t < K) ? bucket_cnt[t] : 0;
    sh[t] = v;
    __syncthreads();
    for (int off = 1; off < 512; off <<= 1) {
        int tv = 0;
        if (t >= off) tv = sh[t - off];
        __syncthreads();
        if (t >= off) sh[t] += tv;
        __syncthreads();
    }
    if (t < K) {
        int b = sh[t] - v;
        bucket_base[t] = b;
        cursor[t] = b;
    }
    if (t == 511) bucket_base[K] = sh[511];
}

__global__ void bucketB(const int* __restrict__ src, const int* __restrict__ dst,
                        const int* __restrict__ etype, int* __restrict__ cursor,
                        int* __restrict__ tmp, int E) {
    __shared__ int cnt[512];
    int tid = threadIdx.x;
    for (int i = tid; i < 512; i += 256) cnt[i] = 0;
    __syncthreads();
    int base = blockIdx.x * 4096;
    int lrank[16], pk[16], bk[16];
#pragma unroll
    for (int k = 0; k < 16; k++) {
        int e = base + k * 256 + tid;
        if (e < E) {
            int d = dst[e];
            int b = d >> BSH;
            bk[k] = b;
            pk[k] = src[e] | (etype[e] << 17) | ((d & 255) << 20);
            lrank[k] = atomicAdd(&cnt[b], 1);
        } else {
            bk[k] = -1;
        }
    }
    __syncthreads();
    for (int i = tid; i < 512; i += 256) {
        int c = cnt[i];
        if (c) cnt[i] = atomicAdd(&cursor[i], c);
    }
    __syncthreads();
#pragma unroll
    for (int k = 0; k < 16; k++) {
        if (bk[k] >= 0) tmp[cnt[bk[k]] + lrank[k]] = pk[k];
    }
}

__global__ void bucketC(const int* __restrict__ bucket_base, const int* __restrict__ tmp,
                        int* __restrict__ es, int* __restrict__ row_start,
                        int N, int E, int K) {
    __shared__ int stor[BCAP];
    __shared__ int hist[256];
    __shared__ int sc[256];
    __shared__ int cur[256];
    int b = blockIdx.x;
    int tid = threadIdx.x;
    int beg = bucket_base[b], end = bucket_base[b + 1];
    int cnt = end - beg;
    hist[tid] = 0;
    __syncthreads();
    for (int i = tid; i < cnt; i += 256) {
        int p = tmp[beg + i];
        if (i < BCAP) stor[i] = p;
        atomicAdd(&hist[p >> 20], 1);
    }
    __syncthreads();
    int v = hist[tid];
    sc[tid] = v;
    __syncthreads();
    for (int off = 1; off < 256; off <<= 1) {
        int tv = 0;
        if (tid >= off) tv = sc[tid - off];
        __syncthreads();
        if (tid >= off) sc[tid] += tv;
        __syncthreads();
    }
    int excl = sc[tid] - v;
    int d = (b << BSH) + tid;
    if (d < N) row_start[d] = beg + excl;
    if (b == K - 1 && tid == 0) row_start[N] = E;
    cur[tid] = beg + excl;
    __syncthreads();
    for (int i = tid; i < cnt; i += 256) {
        int p = (i < BCAP) ? stor[i] : tmp[beg + i];
        int ld = p >> 20;
        int pos = atomicAdd(&cur[ld], 1);
        es[pos] = (p & 0x1FFFF) | (((p >> 17) & 7) << 20);
    }
}

// ---------------- per-layer kernels ----------------

// LDS-tiled, spill-safe: 64 nodes/block. Thread = (node-group g of 8, col q).
template<int IN>
__global__ void __launch_bounds__(256, 2)
xrsb_kernel(const float* __restrict__ xin, int xstride,
            const float* __restrict__ bases,  // [2, IN, 32]
            const float* __restrict__ comp,   // [R, 2]
            const float* __restrict__ loopw,  // [IN, 32]
            const float* __restrict__ bias,   // [32]
            __half* __restrict__ xr, float* __restrict__ selfb, int N) {
    __shared__ float Wt[192 * (IN + 1)];
    __shared__ float xt[64 * IN];
    int tid = threadIdx.x;
    int n0 = blockIdx.x * 64;

    for (int idx = tid; idx < 192 * IN; idx += 256) {
        int j = idx / IN, k = idx - j * IN;
        float w;
        if (j < 160) {
            int r = j >> 5, c = j & 31;
            w = fmaf(comp[2 * r], bases[k * HID + c],
                     comp[2 * r + 1] * bases[(IN + k) * HID + c]);
        } else {
            w = loopw[k * HID + (j - 160)];
        }
        Wt[j * (IN + 1) + k] = w;
    }
    constexpr int Q = IN / 4;
    for (int idx = tid; idx < 64 * Q; idx += 256) {
        int m = idx / Q, kq = idx - m * Q;
        int n = n0 + m;
        float4 v = make_float4(0.f, 0.f, 0.f, 0.f);
        if (n < N) v = ((const float4*)(xin + (size_t)n * xstride))[kq];
        *(float4*)&xt[m * IN + kq * 4] = v;
    }
    __syncthreads();

    int q = tid & 31, g = tid >> 5;
    int m0 = g * 8;
    float acc[6][8];
#pragma unroll
    for (int s = 0; s < 6; s++)
#pragma unroll
        for (int m = 0; m < 8; m++) acc[s][m] = 0.f;

    for (int k4 = 0; k4 < IN; k4 += 4) {
        float4 xv[8];
#pragma unroll
        for (int m = 0; m < 8; m++)
            xv[m] = *(const float4*)&xt[(m0 + m) * IN + k4];
#pragma unroll
        for (int kk = 0; kk < 4; kk++) {
            float w[6];
#pragma unroll
            for (int s = 0; s < 6; s++)
                w[s] = Wt[(q + 32 * s) * (IN + 1) + k4 + kk];
#pragma unroll
            for (int m = 0; m < 8; m++) {
                float xk = (&xv[m].x)[kk];
#pragma unroll
                for (int s = 0; s < 6; s++)
                    acc[s][m] = fmaf(xk, w[s], acc[s][m]);
            }
        }
    }

    float bq = bias[q];
#pragma unroll
    for (int m = 0; m < 8; m++) {
        int n = n0 + m0 + m;
        if (n >= N) break;
#pragma unroll
        for (int s = 0; s < 5; s++)
            xr[((size_t)s * N + n) * HID + q] = __float2half(acc[s][m]);
        selfb[(size_t)n * HID + q] = acc[5][m] + bq;
    }
}

// 8 lanes per dst row, uint2 loads; 3-stage software pipeline:
// idx batch b+1 is issued BEFORE gathers of batch b, so the accumulate's
// waitcnt (oldest ops) never drains the younger gather/idx loads.
__global__ void __launch_bounds__(256, 4)
agg_kernel(const int* __restrict__ row_start, const int* __restrict__ es,
           const __half* __restrict__ xr, const float* __restrict__ selfb,
           float* __restrict__ C, int col_off, int N) {
    int gid = blockIdx.x * blockDim.x + threadIdx.x;
    int d = gid >> 3;
    if (d >= N) return;
    int c4 = gid & 7;
    int beg = row_start[d], end = row_start[d + 1];
    float a0 = 0.f, a1 = 0.f, a2 = 0.f, a3 = 0.f;
    int nb = (end - beg) >> 3;
    int i = beg;

    if (nb >= 1) {
        int p[8], pn[8];
#pragma unroll
        for (int k = 0; k < 8; k++) p[k] = es[i + k];
        if (nb >= 2) {
#pragma unroll
            for (int k = 0; k < 8; k++) pn[k] = es[i + 8 + k];
        }
        uint2 va[8];
#pragma unroll
        for (int k = 0; k < 8; k++) {
            size_t row = (size_t)(p[k] >> 20) * N + (p[k] & 0xFFFFF);
            va[k] = ((const uint2*)(xr + row * HID))[c4];
        }
        for (int b = 1; b < nb; b++) {
            int pt[8];
#pragma unroll
            for (int k = 0; k < 8; k++) pt[k] = pn[k];   // waits idx batch b only
            if (b + 1 < nb) {
#pragma unroll
                for (int k = 0; k < 8; k++) pn[k] = es[i + (b + 1) * 8 + k];
            }
            uint2 vb[8];
#pragma unroll
            for (int k = 0; k < 8; k++) {
                size_t row = (size_t)(pt[k] >> 20) * N + (pt[k] & 0xFFFFF);
                vb[k] = ((const uint2*)(xr + row * HID))[c4];
            }
#pragma unroll
            for (int k = 0; k < 8; k++) {                // waits gathers b-1 only
                float2 lo = __half22float2(*reinterpret_cast<__half2*>(&va[k].x));
                float2 hi = __half22float2(*reinterpret_cast<__half2*>(&va[k].y));
                a0 += lo.x; a1 += lo.y; a2 += hi.x; a3 += hi.y;
            }
#pragma unroll
            for (int k = 0; k < 8; k++) va[k] = vb[k];
        }
#pragma unroll
        for (int k = 0; k < 8; k++) {
            float2 lo = __half22float2(*reinterpret_cast<__half2*>(&va[k].x));
            float2 hi = __half22float2(*reinterpret_cast<__half2*>(&va[k].y));
            a0 += lo.x; a1 += lo.y; a2 += hi.x; a3 += hi.y;
        }
        i += nb * 8;
    }
    for (; i < end; i++) {
        int p = es[i];
        size_t row = (size_t)(p >> 20) * N + (p & 0xFFFFF);
        uint2 vv = ((const uint2*)(xr + row * HID))[c4];
        float2 lo = __half22float2(*reinterpret_cast<__half2*>(&vv.x));
        float2 hi = __half22float2(*reinterpret_cast<__half2*>(&vv.y));
        a0 += lo.x; a1 += lo.y; a2 += hi.x; a3 += hi.y;
    }
    int c = c4 * 4;
    const float4 sb = *(const float4*)(selfb + (size_t)d * HID + c);
    float4 h;
    h.x = fast_tanh(a0 + sb.x);
    h.y = fast_tanh(a1 + sb.y);
    h.z = fast_tanh(a2 + sb.z);
    h.w = fast_tanh(a3 + sb.w);
    *(float4*)(C + (size_t)d * 128 + col_off + c) = h;
}

// ---------------- final MLP ----------------
#define MP 16
__global__ void __launch_bounds__(256, 4)
mlp_kernel(const float* __restrict__ C, const int* __restrict__ uid,
           const int* __restrict__ vid, const float* __restrict__ w1,
           const float* __restrict__ bl1, const float* __restrict__ w2,
           const float* __restrict__ bl2, float* __restrict__ out, int G) {
    __shared__ float feat[MP][2][128];
    __shared__ float psum[MP][128];
    int g0 = blockIdx.x * MP;
    int tid = threadIdx.x;

    for (int idx = tid; idx < MP * 64; idx += 256) {
        int g = idx >> 6;
        int rem = idx & 63;
        int which = rem >> 5;
        int q4 = rem & 31;
        int gg = g0 + g;
        float4 v = make_float4(0.f, 0.f, 0.f, 0.f);
        if (gg < G) {
            int node = which ? vid[gg] : uid[gg];
            v = ((const float4*)(C + (size_t)node * 128))[q4];
        }
        *(float4*)&feat[g][which][q4 * 4] = v;
    }
    __syncthreads();

    int q32 = tid & 31;
    int gs = (tid >> 5) & 3;
    int h = tid >> 7;
    float acc[4][4];
#pragma unroll
    for (int j = 0; j < 4; j++)
#pragma unroll
        for (int i = 0; i < 4; i++) acc[j][i] = 0.f;

    const float* wbase = w1 + (size_t)(h * 128) * 128 + q32 * 4;
    for (int k = 0; k < 128; k++) {
        float4 wv = *(const float4*)(wbase + (size_t)k * 128);
        float fv[4];
#pragma unroll
        for (int j = 0; j < 4; j++) fv[j] = feat[gs * 4 + j][h][k];
#pragma unroll
        for (int j = 0; j < 4; j++) {
            acc[j][0] = fmaf(fv[j], wv.x, acc[j][0]);
            acc[j][1] = fmaf(fv[j], wv.y, acc[j][1]);
            acc[j][2] = fmaf(fv[j], wv.z, acc[j][2]);
            acc[j][3] = fmaf(fv[j], wv.w, acc[j][3]);
        }
    }

    if (h == 1) {
#pragma unroll
        for (int j = 0; j < 4; j++)
#pragma unroll
            for (int i = 0; i < 4; i++)
                psum[gs * 4 + j][q32 * 4 + i] = acc[j][i];
    }
    __syncthreads();
    if (h == 0) {
#pragma unroll
        for (int j = 0; j < 4; j++) {
#pragma unroll
            for (int i = 0; i < 4; i++) {
                int q = q32 * 4 + i;
                float t = acc[j][i] + psum[gs * 4 + j][q] + bl1[q];
                psum[gs * 4 + j][q] = fmaxf(t, 0.f) * w2[q];
            }
        }
    }
    __syncthreads();

    float b2 = bl2[0];
#pragma unroll
    for (int pass = 0; pass < 2; pass++) {
        int g = (tid >> 5) + pass * 8;
        int l = tid & 31;
        float s = psum[g][l] + psum[g][l + 32] + psum[g][l + 64] + psum[g][l + 96];
        s += __shfl_down(s, 16, 32);
        s += __shfl_down(s, 8, 32);
        s += __shfl_down(s, 4, 32);
        s += __shfl_down(s, 2, 32);
        s += __shfl_down(s, 1, 32);
        if (l == 0 && g0 + g < G) out[g0 + g] = s + b2;
    }
}

extern "C" void kernel_launch(void* const* d_in, const int* in_sizes, int n_in,
                              void* d_out, int out_size, void* d_ws, size_t ws_size,
                              hipStream_t stream) {
    const float* x   = (const float*)d_in[0];
    const int* src   = (const int*)d_in[1];
    const int* dst   = (const int*)d_in[2];
    const int* etype = (const int*)d_in[3];
    const int* uid   = (const int*)d_in[4];
    const int* vid   = (const int*)d_in[5];
    int N = in_sizes[0] / 4;
    int E = in_sizes[1];
    int G = in_sizes[4];
    int K = (N + 255) >> BSH;

    char* wp = (char*)d_ws;
    auto alloc = [&](size_t bytes) {
        char* p = wp;
        wp += (bytes + 255) & ~(size_t)255;
        return p;
    };
    int* row_start   = (int*)alloc((N + 1) * 4);
    int* bucket_cnt  = (int*)alloc(512 * 4);
    int* bucket_base = (int*)alloc(513 * 4);
    int* cursor      = (int*)alloc(512 * 4);
    int* es          = (int*)alloc((size_t)E * 4);
    __half* xr       = (__half*)alloc((size_t)R * N * HID * 2);
    int* tmp         = (int*)xr;   // aliases xr (consumed by bucketC before xr is written)
    float* selfb     = (float*)alloc((size_t)N * HID * 4);
    float* C         = (float*)alloc((size_t)N * 128 * 4);

    int ebb = (E + 4095) / 4096;
    int xb = (N + 63) / 64;
    int agg_blocks = (N * 8 + 255) / 256;

    // ---- CSR build ----
    hipMemsetAsync(bucket_cnt, 0, 512 * 4, stream);
    bucketA<<<ebb, 256, 0, stream>>>(dst, bucket_cnt, E, K);
    scan_buckets<<<1, 512, 0, stream>>>(bucket_cnt, bucket_base, cursor, K, E);
    bucketB<<<ebb, 256, 0, stream>>>(src, dst, etype, cursor, tmp, E);
    bucketC<<<K, 256, 0, stream>>>(bucket_base, tmp, es, row_start, N, E, K);

    // ---- layers ----
    for (int l = 0; l < 4; l++) {
        const float* bases = (const float*)d_in[6 + l * 4];
        const float* comp  = (const float*)d_in[7 + l * 4];
        const float* loopw = (const float*)d_in[8 + l * 4];
        const float* bias  = (const float*)d_in[9 + l * 4];
        if (l == 0)
            xrsb_kernel<4><<<xb, 256, 0, stream>>>(x, 4, bases, comp, loopw, bias,
                                                   xr, selfb, N);
        else
            xrsb_kernel<32><<<xb, 256, 0, stream>>>(C + (l - 1) * HID, 128, bases, comp,
                                                    loopw, bias, xr, selfb, N);
        agg_kernel<<<agg_blocks, 256, 0, stream>>>(row_start, es, xr, selfb, C, l * HID, N);
    }

    int gblocks = (G + MP - 1) / MP;
    mlp_kernel<<<gblocks, 256, 0, stream>>>(C, uid, vid,
                                            (const float*)d_in[22], (const float*)d_in[23],
                                            (const float*)d_in[24], (const float*)d_in[25],
                                            (float*)d_out, G);
}

// Round 9
// 470.926 us; speedup vs baseline: 6.9597x; 1.4385x over previous
//
#include <hip/hip_runtime.h>
#include <hip/hip_fp16.h>

#define HID 32
#define R 5
#define BSH 8            // bucket shift: 256 nodes per bucket
#define BCAP 12288       // LDS staging capacity in bucketC (48 KB)

__device__ __forceinline__ float fast_tanh(float x) {
    x = fminf(15.f, fmaxf(-15.f, x));
    float e = __expf(2.f * x);
    return (e - 1.f) / (e + 1.f);
}

// ---------------- CSR build: bucketed 2-level counting sort ----------------

__global__ void zero_kernel(int* p, int n) {
    int i = blockIdx.x * blockDim.x + threadIdx.x;
    if (i < n) p[i] = 0;
}

__global__ void bucketA(const int* __restrict__ dst, int* __restrict__ bucket_cnt,
                        int E, int K) {
    __shared__ int h[512];
    for (int i = threadIdx.x; i < K; i += 256) h[i] = 0;
    __syncthreads();
    int base = blockIdx.x * 4096;
#pragma unroll
    for (int k = 0; k < 16; k++) {
        int e = base + k * 256 + threadIdx.x;
        if (e < E) atomicAdd(&h[dst[e] >> BSH], 1);
    }
    __syncthreads();
    for (int i = threadIdx.x; i < K; i += 256)
        if (h[i]) atomicAdd(&bucket_cnt[i], h[i]);
}

__global__ void scan_buckets(const int* __restrict__ bucket_cnt, int* __restrict__ bucket_base,
                             int* __restrict__ cursor, int K, int E) {
    __shared__ int sh[512];
    int t = threadIdx.x;
    int v = (t < K) ? bucket_cnt[t] : 0;
    sh[t] = v;
    __syncthreads();
    for (int off = 1; off < 512; off <<= 1) {
        int tv = 0;
        if (t >= off) tv = sh[t - off];
        __syncthreads();
        if (t >= off) sh[t] += tv;
        __syncthreads();
    }
    if (t < K) {
        int b = sh[t] - v;
        bucket_base[t] = b;
        cursor[t] = b;
    }
    if (t == 511) bucket_base[K] = sh[511];
}

__global__ void bucketB(const int* __restrict__ src, const int* __restrict__ dst,
                        const int* __restrict__ etype, int* __restrict__ cursor,
                        int* __restrict__ tmp, int E) {
    __shared__ int cnt[512];
    int tid = threadIdx.x;
    for (int i = tid; i < 512; i += 256) cnt[i] = 0;
    __syncthreads();
    int base = blockIdx.x * 4096;
    int lrank[16], pk[16], bk[16];
#pragma unroll
    for (int k = 0; k < 16; k++) {
        int e = base + k * 256 + tid;
        if (e < E) {
            int d = dst[e];
            int b = d >> BSH;
            bk[k] = b;
            pk[k] = src[e] | (etype[e] << 17) | ((d & 255) << 20);
            lrank[k] = atomicAdd(&cnt[b], 1);
        } else {
            bk[k] = -1;
        }
    }
    __syncthreads();
    for (int i = tid; i < 512; i += 256) {
        int c = cnt[i];
        if (c) cnt[i] = atomicAdd(&cursor[i], c);
    }
    __syncthreads();
#pragma unroll
    for (int k = 0; k < 16; k++) {
        if (bk[k] >= 0) tmp[cnt[bk[k]] + lrank[k]] = pk[k];
    }
}

__global__ void bucketC(const int* __restrict__ bucket_base, const int* __restrict__ tmp,
                        int* __restrict__ es, int* __restrict__ row_start,
                        int N, int E, int K) {
    __shared__ int stor[BCAP];
    __shared__ int hist[256];
    __shared__ int sc[256];
    __shared__ int cur[256];
    int b = blockIdx.x;
    int tid = threadIdx.x;
    int beg = bucket_base[b], end = bucket_base[b + 1];
    int cnt = end - beg;
    hist[tid] = 0;
    __syncthreads();
    for (int i = tid; i < cnt; i += 256) {
        int p = tmp[beg + i];
        if (i < BCAP) stor[i] = p;
        atomicAdd(&hist[p >> 20], 1);
    }
    __syncthreads();
    int v = hist[tid];
    sc[tid] = v;
    __syncthreads();
    for (int off = 1; off < 256; off <<= 1) {
        int tv = 0;
        if (tid >= off) tv = sc[tid - off];
        __syncthreads();
        if (tid >= off) sc[tid] += tv;
        __syncthreads();
    }
    int excl = sc[tid] - v;
    int d = (b << BSH) + tid;
    if (d < N) row_start[d] = beg + excl;
    if (b == K - 1 && tid == 0) row_start[N] = E;
    cur[tid] = beg + excl;
    __syncthreads();
    for (int i = tid; i < cnt; i += 256) {
        int p = (i < BCAP) ? stor[i] : tmp[beg + i];
        int ld = p >> 20;
        int pos = atomicAdd(&cur[ld], 1);
        es[pos] = (p & 0x1FFFF) | (((p >> 17) & 7) << 20);
    }
}

// ---------------- layer 0: gather fp32 x rows (16 B), fused transform ----------------
// agg[d] = sum_b B_b^T S_b[d] + loop0^T x[d] + b0;  S_b[d] = sum_e comp[et,b] x[src]
// 256 thr = 128 dst-groups x 2 lanes (lane = basis b).
__global__ void __launch_bounds__(256, 4)
agg0_kernel(const int* __restrict__ row_start, const int* __restrict__ es,
            const float* __restrict__ x,
            const float* __restrict__ bases,  // [2,4,32]
            const float* __restrict__ comp,   // [5,2]
            const float* __restrict__ loopw,  // [4,32]
            const float* __restrict__ bias,   // [32]
            float* __restrict__ C, __half* __restrict__ xh_out, int N) {
    __shared__ float Wl[12 * 32];       // [k][c]: k=b*4+i (b<2), k=8+i -> loopw
    __shared__ float comp_l[10];
    __shared__ float S[128][13];        // [dstloc][k: 0..7 bases acc, 8..11 self x]
    int tid = threadIdx.x;
    if (tid < 10) comp_l[tid] = comp[tid];
    for (int idx = tid; idx < 384; idx += 256) {
        int k = idx >> 5, c = idx & 31;
        Wl[idx] = (k < 8) ? bases[(k >> 2) * 128 + (k & 3) * 32 + c]
                          : loopw[(k - 8) * 32 + c];
    }
    __syncthreads();

    int g = tid >> 1, b = tid & 1;
    int d = blockIdx.x * 128 + g;
    bool valid = d < N;
    int beg = valid ? row_start[d] : 0;
    int end = valid ? row_start[d + 1] : 0;
    float4 acc = make_float4(0.f, 0.f, 0.f, 0.f);

    int nb = (end - beg) >> 2;
    int i = beg;
    if (nb >= 1) {
        int p[4], pn[4];
#pragma unroll
        for (int k = 0; k < 4; k++) p[k] = es[i + k];
        if (nb >= 2) {
#pragma unroll
            for (int k = 0; k < 4; k++) pn[k] = es[i + 4 + k];
        }
        float4 va[4]; float ca[4];
#pragma unroll
        for (int k = 0; k < 4; k++) {
            int s = p[k] & 0x1FFFF, et = p[k] >> 20;
            ca[k] = comp_l[et * 2 + b];
            va[k] = *(const float4*)(x + (size_t)s * 4);
        }
        for (int bb = 1; bb < nb; bb++) {
            int pt[4];
#pragma unroll
            for (int k = 0; k < 4; k++) pt[k] = pn[k];
            if (bb + 1 < nb) {
#pragma unroll
                for (int k = 0; k < 4; k++) pn[k] = es[i + (bb + 1) * 4 + k];
            }
            float4 vb[4]; float cb[4];
#pragma unroll
            for (int k = 0; k < 4; k++) {
                int s = pt[k] & 0x1FFFF, et = pt[k] >> 20;
                cb[k] = comp_l[et * 2 + b];
                vb[k] = *(const float4*)(x + (size_t)s * 4);
            }
#pragma unroll
            for (int k = 0; k < 4; k++) {
                acc.x = fmaf(ca[k], va[k].x, acc.x);
                acc.y = fmaf(ca[k], va[k].y, acc.y);
                acc.z = fmaf(ca[k], va[k].z, acc.z);
                acc.w = fmaf(ca[k], va[k].w, acc.w);
            }
#pragma unroll
            for (int k = 0; k < 4; k++) { va[k] = vb[k]; ca[k] = cb[k]; }
        }
#pragma unroll
        for (int k = 0; k < 4; k++) {
            acc.x = fmaf(ca[k], va[k].x, acc.x);
            acc.y = fmaf(ca[k], va[k].y, acc.y);
            acc.z = fmaf(ca[k], va[k].z, acc.z);
            acc.w = fmaf(ca[k], va[k].w, acc.w);
        }
        i += nb * 4;
    }
    for (; i < end; i++) {
        int p = es[i];
        int s = p & 0x1FFFF, et = p >> 20;
        float cc = comp_l[et * 2 + b];
        float4 v = *(const float4*)(x + (size_t)s * 4);
        acc.x = fmaf(cc, v.x, acc.x);
        acc.y = fmaf(cc, v.y, acc.y);
        acc.z = fmaf(cc, v.z, acc.z);
        acc.w = fmaf(cc, v.w, acc.w);
    }
    S[g][b * 4 + 0] = acc.x;
    S[g][b * 4 + 1] = acc.y;
    S[g][b * 4 + 2] = acc.z;
    S[g][b * 4 + 3] = acc.w;
    if (b == 0) {
        float4 xs = valid ? *(const float4*)(x + (size_t)d * 4)
                          : make_float4(0.f, 0.f, 0.f, 0.f);
        S[g][8] = xs.x; S[g][9] = xs.y; S[g][10] = xs.z; S[g][11] = xs.w;
    }
    __syncthreads();

    int c4 = tid & 7;
    float4 bi = *(const float4*)(bias + c4 * 4);
#pragma unroll
    for (int rr = 0; rr < 4; rr++) {
        int g2 = (tid >> 3) + 32 * rr;
        int d2 = blockIdx.x * 128 + g2;
        float4 o = bi;
#pragma unroll
        for (int k = 0; k < 12; k++) {
            float s = S[g2][k];
            float4 w = *(const float4*)&Wl[k * 32 + c4 * 4];
            o.x = fmaf(s, w.x, o.x);
            o.y = fmaf(s, w.y, o.y);
            o.z = fmaf(s, w.z, o.z);
            o.w = fmaf(s, w.w, o.w);
        }
        if (d2 < N) {
            float4 h;
            h.x = fast_tanh(o.x); h.y = fast_tanh(o.y);
            h.z = fast_tanh(o.z); h.w = fast_tanh(o.w);
            *(float4*)(C + (size_t)d2 * 128 + c4 * 4) = h;
            __half2 p0 = __floats2half2_rn(h.x, h.y);
            __half2 p1 = __floats2half2_rn(h.z, h.w);
            uint2 o2 = make_uint2(*(unsigned*)&p0, *(unsigned*)&p1);
            ((uint2*)(xh_out + (size_t)d2 * HID))[c4] = o2;
        }
    }
}

// ---------------- layers 1-3: gather fp16 h rows (64 B/row, 6.4 MB table) ----------------
// 256 thr = 32 dst-groups x 8 lanes (lane = 4 channels).
template<bool WRITE_XH>
__global__ void __launch_bounds__(256, 4)
agg_fused(const int* __restrict__ row_start, const int* __restrict__ es,
          const __half* __restrict__ xh_in,
          const float* __restrict__ bases,  // [2,32,32]
          const float* __restrict__ comp,   // [5,2]
          const float* __restrict__ loopw,  // [32,32]
          const float* __restrict__ bias,   // [32]
          float* __restrict__ C, __half* __restrict__ xh_out, int col_off, int N) {
    __shared__ float Wl[96 * 32];      // [k][c]: k<64 bases, 64..95 loopw
    __shared__ float comp_l[10];
    __shared__ float S[32][97];        // [dstloc][k: 0..63 base acc, 64..95 self h]
    int tid = threadIdx.x;
    if (tid < 10) comp_l[tid] = comp[tid];
    for (int idx = tid; idx < 96 * 32; idx += 256)
        Wl[idx] = (idx < 2048) ? bases[idx] : loopw[idx - 2048];
    __syncthreads();

    int g = tid >> 3, c4 = tid & 7;
    int d = blockIdx.x * 32 + g;
    bool valid = d < N;
    int beg = valid ? row_start[d] : 0;
    int end = valid ? row_start[d + 1] : 0;
    float4 a0 = make_float4(0.f, 0.f, 0.f, 0.f);
    float4 a1 = make_float4(0.f, 0.f, 0.f, 0.f);

    int nb = (end - beg) >> 3;
    int i = beg;
    if (nb >= 1) {
        int p[8], pn[8];
#pragma unroll
        for (int k = 0; k < 8; k++) p[k] = es[i + k];
        if (nb >= 2) {
#pragma unroll
            for (int k = 0; k < 8; k++) pn[k] = es[i + 8 + k];
        }
        uint2 va[8]; float c0a[8], c1a[8];
#pragma unroll
        for (int k = 0; k < 8; k++) {
            int s = p[k] & 0x1FFFF, et = p[k] >> 20;
            c0a[k] = comp_l[et * 2];
            c1a[k] = comp_l[et * 2 + 1];
            va[k] = ((const uint2*)(xh_in + (size_t)s * HID))[c4];
        }
        for (int bb = 1; bb < nb; bb++) {
            int pt[8];
#pragma unroll
            for (int k = 0; k < 8; k++) pt[k] = pn[k];
            if (bb + 1 < nb) {
#pragma unroll
                for (int k = 0; k < 8; k++) pn[k] = es[i + (bb + 1) * 8 + k];
            }
            uint2 vb[8]; float c0b[8], c1b[8];
#pragma unroll
            for (int k = 0; k < 8; k++) {
                int s = pt[k] & 0x1FFFF, et = pt[k] >> 20;
                c0b[k] = comp_l[et * 2];
                c1b[k] = comp_l[et * 2 + 1];
                vb[k] = ((const uint2*)(xh_in + (size_t)s * HID))[c4];
            }
#pragma unroll
            for (int k = 0; k < 8; k++) {
                float2 lo = __half22float2(*reinterpret_cast<__half2*>(&va[k].x));
                float2 hi = __half22float2(*reinterpret_cast<__half2*>(&va[k].y));
                a0.x = fmaf(c0a[k], lo.x, a0.x); a1.x = fmaf(c1a[k], lo.x, a1.x);
                a0.y = fmaf(c0a[k], lo.y, a0.y); a1.y = fmaf(c1a[k], lo.y, a1.y);
                a0.z = fmaf(c0a[k], hi.x, a0.z); a1.z = fmaf(c1a[k], hi.x, a1.z);
                a0.w = fmaf(c0a[k], hi.y, a0.w); a1.w = fmaf(c1a[k], hi.y, a1.w);
            }
#pragma unroll
            for (int k = 0; k < 8; k++) { va[k] = vb[k]; c0a[k] = c0b[k]; c1a[k] = c1b[k]; }
        }
#pragma unroll
        for (int k = 0; k < 8; k++) {
            float2 lo = __half22float2(*reinterpret_cast<__half2*>(&va[k].x));
            float2 hi = __half22float2(*reinterpret_cast<__half2*>(&va[k].y));
            a0.x = fmaf(c0a[k], lo.x, a0.x); a1.x = fmaf(c1a[k], lo.x, a1.x);
            a0.y = fmaf(c0a[k], lo.y, a0.y); a1.y = fmaf(c1a[k], lo.y, a1.y);
            a0.z = fmaf(c0a[k], hi.x, a0.z); a1.z = fmaf(c1a[k], hi.x, a1.z);
            a0.w = fmaf(c0a[k], hi.y, a0.w); a1.w = fmaf(c1a[k], hi.y, a1.w);
        }
        i += nb * 8;
    }
    for (; i < end; i++) {
        int p = es[i];
        int s = p & 0x1FFFF, et = p >> 20;
        float c0 = comp_l[et * 2], c1 = comp_l[et * 2 + 1];
        uint2 vv = ((const uint2*)(xh_in + (size_t)s * HID))[c4];
        float2 lo = __half22float2(*reinterpret_cast<__half2*>(&vv.x));
        float2 hi = __half22float2(*reinterpret_cast<__half2*>(&vv.y));
        a0.x = fmaf(c0, lo.x, a0.x); a1.x = fmaf(c1, lo.x, a1.x);
        a0.y = fmaf(c0, lo.y, a0.y); a1.y = fmaf(c1, lo.y, a1.y);
        a0.z = fmaf(c0, hi.x, a0.z); a1.z = fmaf(c1, hi.x, a1.z);
        a0.w = fmaf(c0, hi.y, a0.w); a1.w = fmaf(c1, hi.y, a1.w);
    }
    *(float4*)&S[g][c4 * 4] = a0;
    *(float4*)&S[g][32 + c4 * 4] = a1;
    {   // self row
        uint2 vv = valid ? ((const uint2*)(xh_in + (size_t)d * HID))[c4]
                         : make_uint2(0u, 0u);
        float2 lo = __half22float2(*reinterpret_cast<__half2*>(&vv.x));
        float2 hi = __half22float2(*reinterpret_cast<__half2*>(&vv.y));
        S[g][64 + c4 * 4 + 0] = lo.x;
        S[g][64 + c4 * 4 + 1] = lo.y;
        S[g][64 + c4 * 4 + 2] = hi.x;
        S[g][64 + c4 * 4 + 3] = hi.y;
    }
    __syncthreads();

    float4 o = *(const float4*)(bias + c4 * 4);
#pragma unroll 8
    for (int k = 0; k < 96; k++) {
        float s = S[g][k];
        float4 w = *(const float4*)&Wl[k * 32 + c4 * 4];
        o.x = fmaf(s, w.x, o.x);
        o.y = fmaf(s, w.y, o.y);
        o.z = fmaf(s, w.z, o.z);
        o.w = fmaf(s, w.w, o.w);
    }
    if (valid) {
        float4 h;
        h.x = fast_tanh(o.x); h.y = fast_tanh(o.y);
        h.z = fast_tanh(o.z); h.w = fast_tanh(o.w);
        *(float4*)(C + (size_t)d * 128 + col_off + c4 * 4) = h;
        if (WRITE_XH) {
            __half2 p0 = __floats2half2_rn(h.x, h.y);
            __half2 p1 = __floats2half2_rn(h.z, h.w);
            uint2 o2 = make_uint2(*(unsigned*)&p0, *(unsigned*)&p1);
            ((uint2*)(xh_out + (size_t)d * HID))[c4] = o2;
        }
    }
}

// ---------------- final MLP ----------------
#define MP 16
__global__ void __launch_bounds__(256, 4)
mlp_kernel(const float* __restrict__ C, const int* __restrict__ uid,
           const int* __restrict__ vid, const float* __restrict__ w1,
           const float* __restrict__ bl1, const float* __restrict__ w2,
           const float* __restrict__ bl2, float* __restrict__ out, int G) {
    __shared__ float feat[MP][2][128];
    __shared__ float psum[MP][128];
    int g0 = blockIdx.x * MP;
    int tid = threadIdx.x;

    for (int idx = tid; idx < MP * 64; idx += 256) {
        int g = idx >> 6;
        int rem = idx & 63;
        int which = rem >> 5;
        int q4 = rem & 31;
        int gg = g0 + g;
        float4 v = make_float4(0.f, 0.f, 0.f, 0.f);
        if (gg < G) {
            int node = which ? vid[gg] : uid[gg];
            v = ((const float4*)(C + (size_t)node * 128))[q4];
        }
        *(float4*)&feat[g][which][q4 * 4] = v;
    }
    __syncthreads();

    int q32 = tid & 31;
    int gs = (tid >> 5) & 3;
    int h = tid >> 7;
    float acc[4][4];
#pragma unroll
    for (int j = 0; j < 4; j++)
#pragma unroll
        for (int i = 0; i < 4; i++) acc[j][i] = 0.f;

    const float* wbase = w1 + (size_t)(h * 128) * 128 + q32 * 4;
    for (int k = 0; k < 128; k++) {
        float4 wv = *(const float4*)(wbase + (size_t)k * 128);
        float fv[4];
#pragma unroll
        for (int j = 0; j < 4; j++) fv[j] = feat[gs * 4 + j][h][k];
#pragma unroll
        for (int j = 0; j < 4; j++) {
            acc[j][0] = fmaf(fv[j], wv.x, acc[j][0]);
            acc[j][1] = fmaf(fv[j], wv.y, acc[j][1]);
            acc[j][2] = fmaf(fv[j], wv.z, acc[j][2]);
            acc[j][3] = fmaf(fv[j], wv.w, acc[j][3]);
        }
    }

    if (h == 1) {
#pragma unroll
        for (int j = 0; j < 4; j++)
#pragma unroll
            for (int i = 0; i < 4; i++)
                psum[gs * 4 + j][q32 * 4 + i] = acc[j][i];
    }
    __syncthreads();
    if (h == 0) {
#pragma unroll
        for (int j = 0; j < 4; j++) {
#pragma unroll
            for (int i = 0; i < 4; i++) {
                int q = q32 * 4 + i;
                float t = acc[j][i] + psum[gs * 4 + j][q] + bl1[q];
                psum[gs * 4 + j][q] = fmaxf(t, 0.f) * w2[q];
            }
        }
    }
    __syncthreads();

    float b2 = bl2[0];
#pragma unroll
    for (int pass = 0; pass < 2; pass++) {
        int g = (tid >> 5) + pass * 8;
        int l = tid & 31;
        float s = psum[g][l] + psum[g][l + 32] + psum[g][l + 64] + psum[g][l + 96];
        s += __shfl_down(s, 16, 32);
        s += __shfl_down(s, 8, 32);
        s += __shfl_down(s, 4, 32);
        s += __shfl_down(s, 2, 32);
        s += __shfl_down(s, 1, 32);
        if (l == 0 && g0 + g < G) out[g0 + g] = s + b2;
    }
}

extern "C" void kernel_launch(void* const* d_in, const int* in_sizes, int n_in,
                              void* d_out, int out_size, void* d_ws, size_t ws_size,
                              hipStream_t stream) {
    const float* x   = (const float*)d_in[0];
    const int* src   = (const int*)d_in[1];
    const int* dst   = (const int*)d_in[2];
    const int* etype = (const int*)d_in[3];
    const int* uid   = (const int*)d_in[4];
    const int* vid   = (const int*)d_in[5];
    int N = in_sizes[0] / 4;
    int E = in_sizes[1];
    int G = in_sizes[4];
    int K = (N + 255) >> BSH;

    char* wp = (char*)d_ws;
    auto alloc = [&](size_t bytes) {
        char* p = wp;
        wp += (bytes + 255) & ~(size_t)255;
        return p;
    };
    int* row_start   = (int*)alloc((N + 1) * 4);
    int* bucket_cnt  = (int*)alloc(512 * 4);
    int* bucket_base = (int*)alloc(513 * 4);
    int* cursor      = (int*)alloc(512 * 4);
    int* es          = (int*)alloc((size_t)E * 4);
    __half* xhA      = (__half*)alloc((size_t)N * HID * 2);
    __half* xhB      = (__half*)alloc((size_t)N * HID * 2);
    float* C         = (float*)alloc((size_t)N * 128 * 4);
    int* tmp         = (int*)C;   // E ints alias C (consumed by bucketC before C written)

    int ebb = (E + 4095) / 4096;

    // ---- CSR build ----
    zero_kernel<<<2, 256, 0, stream>>>(bucket_cnt, 512);
    bucketA<<<ebb, 256, 0, stream>>>(dst, bucket_cnt, E, K);
    scan_buckets<<<1, 512, 0, stream>>>(bucket_cnt, bucket_base, cursor, K, E);
    bucketB<<<ebb, 256, 0, stream>>>(src, dst, etype, cursor, tmp, E);
    bucketC<<<K, 256, 0, stream>>>(bucket_base, tmp, es, row_start, N, E, K);

    // ---- layer 0 (fp32 x gather, fully fused) ----
    agg0_kernel<<<(N + 127) / 128, 256, 0, stream>>>(
        row_start, es, x,
        (const float*)d_in[6], (const float*)d_in[7],
        (const float*)d_in[8], (const float*)d_in[9],
        C, xhA, N);

    // ---- layers 1-3 (fp16 h gather, fully fused) ----
    int ab = (N + 31) / 32;
    agg_fused<true><<<ab, 256, 0, stream>>>(
        row_start, es, xhA,
        (const float*)d_in[10], (const float*)d_in[11],
        (const float*)d_in[12], (const float*)d_in[13],
        C, xhB, 32, N);
    agg_fused<true><<<ab, 256, 0, stream>>>(
        row_start, es, xhB,
        (const float*)d_in[14], (const float*)d_in[15],
        (const float*)d_in[16], (const float*)d_in[17],
        C, xhA, 64, N);
    agg_fused<false><<<ab, 256, 0, stream>>>(
        row_start, es, xhA,
        (const float*)d_in[18], (const float*)d_in[19],
        (const float*)d_in[20], (const float*)d_in[21],
        C, nullptr, 96, N);

    // ---- final MLP ----
    int gblocks = (G + MP - 1) / MP;
    mlp_kernel<<<gblocks, 256, 0, stream>>>(C, uid, vid,
                                            (const float*)d_in[22], (const float*)d_in[23],
                                            (const float*)d_in[24], (const float*)d_in[25],
                                            (float*)d_out, G);
}

// Round 10
// 432.108 us; speedup vs baseline: 7.5849x; 1.0898x over previous
//
#include <hip/hip_runtime.h>
#include <hip/hip_fp16.h>

#define HID 32
#define R 5
#define BSH 8            // bucket shift: 256 nodes per bucket
#define BCAP 12288       // LDS staging capacity in bucketC (48 KB)

__device__ __forceinline__ float fast_tanh(float x) {
    x = fminf(15.f, fmaxf(-15.f, x));
    float e = __expf(2.f * x);
    return (e - 1.f) / (e + 1.f);
}

// ---------------- CSR build: bucketed 2-level counting sort ----------------

__global__ void zero_kernel(int* p, int n) {
    int i = blockIdx.x * blockDim.x + threadIdx.x;
    if (i < n) p[i] = 0;
}

__global__ void bucketA(const int* __restrict__ dst, int* __restrict__ bucket_cnt,
                        int E, int K) {
    __shared__ int h[512];
    for (int i = threadIdx.x; i < K; i += 256) h[i] = 0;
    __syncthreads();
    int base = blockIdx.x * 4096;
#pragma unroll
    for (int k = 0; k < 16; k++) {
        int e = base + k * 256 + threadIdx.x;
        if (e < E) atomicAdd(&h[dst[e] >> BSH], 1);
    }
    __syncthreads();
    for (int i = threadIdx.x; i < K; i += 256)
        if (h[i]) atomicAdd(&bucket_cnt[i], h[i]);
}

__global__ void scan_buckets(const int* __restrict__ bucket_cnt, int* __restrict__ bucket_base,
                             int* __restrict__ cursor, int K, int E) {
    __shared__ int sh[512];
    int t = threadIdx.x;
    int v = (t < K) ? bucket_cnt[t] : 0;
    sh[t] = v;
    __syncthreads();
    for (int off = 1; off < 512; off <<= 1) {
        int tv = 0;
        if (t >= off) tv = sh[t - off];
        __syncthreads();
        if (t >= off) sh[t] += tv;
        __syncthreads();
    }
    if (t < K) {
        int b = sh[t] - v;
        bucket_base[t] = b;
        cursor[t] = b;
    }
    if (t == 511) bucket_base[K] = sh[511];
}

__global__ void bucketB(const int* __restrict__ src, const int* __restrict__ dst,
                        const int* __restrict__ etype, int* __restrict__ cursor,
                        int* __restrict__ tmp, int E) {
    __shared__ int cnt[512];
    int tid = threadIdx.x;
    for (int i = tid; i < 512; i += 256) cnt[i] = 0;
    __syncthreads();
    int base = blockIdx.x * 4096;
    int lrank[16], pk[16], bk[16];
#pragma unroll
    for (int k = 0; k < 16; k++) {
        int e = base + k * 256 + tid;
        if (e < E) {
            int d = dst[e];
            int b = d >> BSH;
            bk[k] = b;
            pk[k] = src[e] | (etype[e] << 17) | ((d & 255) << 20);
            lrank[k] = atomicAdd(&cnt[b], 1);
        } else {
            bk[k] = -1;
        }
    }
    __syncthreads();
    for (int i = tid; i < 512; i += 256) {
        int c = cnt[i];
        if (c) cnt[i] = atomicAdd(&cursor[i], c);
    }
    __syncthreads();
#pragma unroll
    for (int k = 0; k < 16; k++) {
        if (bk[k] >= 0) tmp[cnt[bk[k]] + lrank[k]] = pk[k];
    }
}

__global__ void bucketC(const int* __restrict__ bucket_base, const int* __restrict__ tmp,
                        int* __restrict__ es, int* __restrict__ row_start,
                        int N, int E, int K) {
    __shared__ int stor[BCAP];
    __shared__ int hist[256];
    __shared__ int sc[256];
    __shared__ int cur[256];
    int b = blockIdx.x;
    int tid = threadIdx.x;
    int beg = bucket_base[b], end = bucket_base[b + 1];
    int cnt = end - beg;
    hist[tid] = 0;
    __syncthreads();
    for (int i = tid; i < cnt; i += 256) {
        int p = tmp[beg + i];
        if (i < BCAP) stor[i] = p;
        atomicAdd(&hist[p >> 20], 1);
    }
    __syncthreads();
    int v = hist[tid];
    sc[tid] = v;
    __syncthreads();
    for (int off = 1; off < 256; off <<= 1) {
        int tv = 0;
        if (tid >= off) tv = sc[tid - off];
        __syncthreads();
        if (tid >= off) sc[tid] += tv;
        __syncthreads();
    }
    int excl = sc[tid] - v;
    int d = (b << BSH) + tid;
    if (d < N) row_start[d] = beg + excl;
    if (b == K - 1 && tid == 0) row_start[N] = E;
    cur[tid] = beg + excl;
    __syncthreads();
    for (int i = tid; i < cnt; i += 256) {
        int p = (i < BCAP) ? stor[i] : tmp[beg + i];
        int ld = p >> 20;
        int pos = atomicAdd(&cur[ld], 1);
        es[pos] = (p & 0x1FFFF) | (((p >> 17) & 7) << 20);
    }
}

// ---------------- layer 0: gather fp32 x rows, fused transform ----------------
// 256 thr = 128 dst-groups x 2 lanes (lane = basis b). Padded-batch pipeline, no scalar tail.
__global__ void __launch_bounds__(256, 4)
agg0_kernel(const int* __restrict__ row_start, const int* __restrict__ es,
            const float* __restrict__ x,
            const float* __restrict__ bases,  // [2,4,32]
            const float* __restrict__ comp,   // [5,2]
            const float* __restrict__ loopw,  // [4,32]
            const float* __restrict__ bias,   // [32]
            float* __restrict__ C, __half* __restrict__ xh_out, int N) {
    __shared__ float Wl[12 * 32];
    __shared__ float comp_l[12];       // [10],[11] = 0 sentinel (et=5)
    __shared__ float S[128][13];
    int tid = threadIdx.x;
    if (tid < 12) comp_l[tid] = (tid < 10) ? comp[tid] : 0.f;
    for (int idx = tid; idx < 384; idx += 256) {
        int k = idx >> 5, c = idx & 31;
        Wl[idx] = (k < 8) ? bases[(k >> 2) * 128 + (k & 3) * 32 + c]
                          : loopw[(k - 8) * 32 + c];
    }
    __syncthreads();

    int g = tid >> 1, b = tid & 1;
    int d = blockIdx.x * 128 + g;
    bool valid = d < N;
    int beg = valid ? row_start[d] : 0;
    int end = valid ? row_start[d + 1] : 0;
    int cnt = end - beg;
    float4 acc = make_float4(0.f, 0.f, 0.f, 0.f);

    const int SENT = 5 << 20;   // et=5 -> coeff 0, src row 0
    int nbt = (cnt + 3) >> 2;
    if (nbt > 0) {
        int p[4], pn[4];
#pragma unroll
        for (int k = 0; k < 4; k++) {
            int j = k;
            p[k] = (j < cnt) ? es[beg + j] : SENT;
        }
        float4 va[4];
#pragma unroll
        for (int k = 0; k < 4; k++)
            va[k] = *(const float4*)(x + (size_t)(p[k] & 0x1FFFF) * 4);
        if (nbt > 1) {
#pragma unroll
            for (int k = 0; k < 4; k++) {
                int j = 4 + k;
                pn[k] = (j < cnt) ? es[beg + j] : SENT;
            }
        }
        for (int bb = 1; bb < nbt; bb++) {
            int pt[4];
#pragma unroll
            for (int k = 0; k < 4; k++) pt[k] = pn[k];
            if (bb + 1 < nbt) {
#pragma unroll
                for (int k = 0; k < 4; k++) {
                    int j = (bb + 1) * 4 + k;
                    pn[k] = (j < cnt) ? es[beg + j] : SENT;
                }
            }
            float4 vb[4];
#pragma unroll
            for (int k = 0; k < 4; k++)
                vb[k] = *(const float4*)(x + (size_t)(pt[k] & 0x1FFFF) * 4);
#pragma unroll
            for (int k = 0; k < 4; k++) {
                float cc = comp_l[(p[k] >> 20) * 2 + b];
                acc.x = fmaf(cc, va[k].x, acc.x);
                acc.y = fmaf(cc, va[k].y, acc.y);
                acc.z = fmaf(cc, va[k].z, acc.z);
                acc.w = fmaf(cc, va[k].w, acc.w);
            }
#pragma unroll
            for (int k = 0; k < 4; k++) { va[k] = vb[k]; p[k] = pt[k]; }
        }
#pragma unroll
        for (int k = 0; k < 4; k++) {
            float cc = comp_l[(p[k] >> 20) * 2 + b];
            acc.x = fmaf(cc, va[k].x, acc.x);
            acc.y = fmaf(cc, va[k].y, acc.y);
            acc.z = fmaf(cc, va[k].z, acc.z);
            acc.w = fmaf(cc, va[k].w, acc.w);
        }
    }
    S[g][b * 4 + 0] = acc.x;
    S[g][b * 4 + 1] = acc.y;
    S[g][b * 4 + 2] = acc.z;
    S[g][b * 4 + 3] = acc.w;
    if (b == 0) {
        float4 xs = valid ? *(const float4*)(x + (size_t)d * 4)
                          : make_float4(0.f, 0.f, 0.f, 0.f);
        S[g][8] = xs.x; S[g][9] = xs.y; S[g][10] = xs.z; S[g][11] = xs.w;
    }
    __syncthreads();

    int c4 = tid & 7;
    float4 bi = *(const float4*)(bias + c4 * 4);
#pragma unroll
    for (int rr = 0; rr < 4; rr++) {
        int g2 = (tid >> 3) + 32 * rr;
        int d2 = blockIdx.x * 128 + g2;
        float4 o = bi;
#pragma unroll
        for (int k = 0; k < 12; k++) {
            float s = S[g2][k];
            float4 w = *(const float4*)&Wl[k * 32 + c4 * 4];
            o.x = fmaf(s, w.x, o.x);
            o.y = fmaf(s, w.y, o.y);
            o.z = fmaf(s, w.z, o.z);
            o.w = fmaf(s, w.w, o.w);
        }
        if (d2 < N) {
            float4 h;
            h.x = fast_tanh(o.x); h.y = fast_tanh(o.y);
            h.z = fast_tanh(o.z); h.w = fast_tanh(o.w);
            *(float4*)(C + (size_t)d2 * 128 + c4 * 4) = h;
            __half2 p0 = __floats2half2_rn(h.x, h.y);
            __half2 p1 = __floats2half2_rn(h.z, h.w);
            uint2 o2 = make_uint2(*(unsigned*)&p0, *(unsigned*)&p1);
            ((uint2*)(xh_out + (size_t)d2 * HID))[c4] = o2;
        }
    }
}

// ---------------- layers 1-3: gather fp16 h rows, fused transform ----------------
// 256 thr = 32 dst-groups x 8 lanes. Padded-batch pipeline, no scalar tail.
template<bool WRITE_XH>
__global__ void __launch_bounds__(256, 4)
agg_fused(const int* __restrict__ row_start, const int* __restrict__ es,
          const __half* __restrict__ xh_in,
          const float* __restrict__ bases,  // [2,32,32]
          const float* __restrict__ comp,   // [5,2]
          const float* __restrict__ loopw,  // [32,32]
          const float* __restrict__ bias,   // [32]
          float* __restrict__ C, __half* __restrict__ xh_out, int col_off, int N) {
    __shared__ float Wl[96 * 32];
    __shared__ float comp_l[12];       // [10],[11] = 0 sentinel (et=5)
    __shared__ float S[32][97];
    int tid = threadIdx.x;
    if (tid < 12) comp_l[tid] = (tid < 10) ? comp[tid] : 0.f;
    for (int idx = tid; idx < 96 * 32; idx += 256)
        Wl[idx] = (idx < 2048) ? bases[idx] : loopw[idx - 2048];
    __syncthreads();

    int g = tid >> 3, c4 = tid & 7;
    int d = blockIdx.x * 32 + g;
    bool valid = d < N;
    int beg = valid ? row_start[d] : 0;
    int end = valid ? row_start[d + 1] : 0;
    int cnt = end - beg;
    float4 a0 = make_float4(0.f, 0.f, 0.f, 0.f);
    float4 a1 = make_float4(0.f, 0.f, 0.f, 0.f);

    const int SENT = 5 << 20;
    int nbt = (cnt + 7) >> 3;
    if (nbt > 0) {
        int p[8], pn[8];
#pragma unroll
        for (int k = 0; k < 8; k++) p[k] = (k < cnt) ? es[beg + k] : SENT;
        uint2 va[8];
#pragma unroll
        for (int k = 0; k < 8; k++)
            va[k] = ((const uint2*)(xh_in + (size_t)(p[k] & 0x1FFFF) * HID))[c4];
        if (nbt > 1) {
#pragma unroll
            for (int k = 0; k < 8; k++) {
                int j = 8 + k;
                pn[k] = (j < cnt) ? es[beg + j] : SENT;
            }
        }
        for (int bb = 1; bb < nbt; bb++) {
            int pt[8];
#pragma unroll
            for (int k = 0; k < 8; k++) pt[k] = pn[k];
            if (bb + 1 < nbt) {
#pragma unroll
                for (int k = 0; k < 8; k++) {
                    int j = (bb + 1) * 8 + k;
                    pn[k] = (j < cnt) ? es[beg + j] : SENT;
                }
            }
            uint2 vb[8];
#pragma unroll
            for (int k = 0; k < 8; k++)
                vb[k] = ((const uint2*)(xh_in + (size_t)(pt[k] & 0x1FFFF) * HID))[c4];
#pragma unroll
            for (int k = 0; k < 8; k++) {
                int et = p[k] >> 20;
                float c0 = comp_l[et * 2], c1 = comp_l[et * 2 + 1];
                float2 lo = __half22float2(*reinterpret_cast<__half2*>(&va[k].x));
                float2 hi = __half22float2(*reinterpret_cast<__half2*>(&va[k].y));
                a0.x = fmaf(c0, lo.x, a0.x); a1.x = fmaf(c1, lo.x, a1.x);
                a0.y = fmaf(c0, lo.y, a0.y); a1.y = fmaf(c1, lo.y, a1.y);
                a0.z = fmaf(c0, hi.x, a0.z); a1.z = fmaf(c1, hi.x, a1.z);
                a0.w = fmaf(c0, hi.y, a0.w); a1.w = fmaf(c1, hi.y, a1.w);
            }
#pragma unroll
            for (int k = 0; k < 8; k++) { va[k] = vb[k]; p[k] = pt[k]; }
        }
#pragma unroll
        for (int k = 0; k < 8; k++) {
            int et = p[k] >> 20;
            float c0 = comp_l[et * 2], c1 = comp_l[et * 2 + 1];
            float2 lo = __half22float2(*reinterpret_cast<__half2*>(&va[k].x));
            float2 hi = __half22float2(*reinterpret_cast<__half2*>(&va[k].y));
            a0.x = fmaf(c0, lo.x, a0.x); a1.x = fmaf(c1, lo.x, a1.x);
            a0.y = fmaf(c0, lo.y, a0.y); a1.y = fmaf(c1, lo.y, a1.y);
            a0.z = fmaf(c0, hi.x, a0.z); a1.z = fmaf(c1, hi.x, a1.z);
            a0.w = fmaf(c0, hi.y, a0.w); a1.w = fmaf(c1, hi.y, a1.w);
        }
    }
    *(float4*)&S[g][c4 * 4] = a0;
    *(float4*)&S[g][32 + c4 * 4] = a1;
    {   // self row
        uint2 vv = valid ? ((const uint2*)(xh_in + (size_t)d * HID))[c4]
                         : make_uint2(0u, 0u);
        float2 lo = __half22float2(*reinterpret_cast<__half2*>(&vv.x));
        float2 hi = __half22float2(*reinterpret_cast<__half2*>(&vv.y));
        S[g][64 + c4 * 4 + 0] = lo.x;
        S[g][64 + c4 * 4 + 1] = lo.y;
        S[g][64 + c4 * 4 + 2] = hi.x;
        S[g][64 + c4 * 4 + 3] = hi.y;
    }
    __syncthreads();

    float4 o = *(const float4*)(bias + c4 * 4);
#pragma unroll 8
    for (int k = 0; k < 96; k++) {
        float s = S[g][k];
        float4 w = *(const float4*)&Wl[k * 32 + c4 * 4];
        o.x = fmaf(s, w.x, o.x);
        o.y = fmaf(s, w.y, o.y);
        o.z = fmaf(s, w.z, o.z);
        o.w = fmaf(s, w.w, o.w);
    }
    if (valid) {
        float4 h;
        h.x = fast_tanh(o.x); h.y = fast_tanh(o.y);
        h.z = fast_tanh(o.z); h.w = fast_tanh(o.w);
        *(float4*)(C + (size_t)d * 128 + col_off + c4 * 4) = h;
        if (WRITE_XH) {
            __half2 p0 = __floats2half2_rn(h.x, h.y);
            __half2 p1 = __floats2half2_rn(h.z, h.w);
            uint2 o2 = make_uint2(*(unsigned*)&p0, *(unsigned*)&p1);
            ((uint2*)(xh_out + (size_t)d * HID))[c4] = o2;
        }
    }
}

// ---------------- final MLP ----------------
#define MP 16
__global__ void __launch_bounds__(256, 4)
mlp_kernel(const float* __restrict__ C, const int* __restrict__ uid,
           const int* __restrict__ vid, const float* __restrict__ w1,
           const float* __restrict__ bl1, const float* __restrict__ w2,
           const float* __restrict__ bl2, float* __restrict__ out, int G) {
    __shared__ float feat[MP][2][128];
    __shared__ float psum[MP][128];
    int g0 = blockIdx.x * MP;
    int tid = threadIdx.x;

    for (int idx = tid; idx < MP * 64; idx += 256) {
        int g = idx >> 6;
        int rem = idx & 63;
        int which = rem >> 5;
        int q4 = rem & 31;
        int gg = g0 + g;
        float4 v = make_float4(0.f, 0.f, 0.f, 0.f);
        if (gg < G) {
            int node = which ? vid[gg] : uid[gg];
            v = ((const float4*)(C + (size_t)node * 128))[q4];
        }
        *(float4*)&feat[g][which][q4 * 4] = v;
    }
    __syncthreads();

    int q32 = tid & 31;
    int gs = (tid >> 5) & 3;
    int h = tid >> 7;
    float acc[4][4];
#pragma unroll
    for (int j = 0; j < 4; j++)
#pragma unroll
        for (int i = 0; i < 4; i++) acc[j][i] = 0.f;

    const float* wbase = w1 + (size_t)(h * 128) * 128 + q32 * 4;
    for (int k = 0; k < 128; k++) {
        float4 wv = *(const float4*)(wbase + (size_t)k * 128);
        float fv[4];
#pragma unroll
        for (int j = 0; j < 4; j++) fv[j] = feat[gs * 4 + j][h][k];
#pragma unroll
        for (int j = 0; j < 4; j++) {
            acc[j][0] = fmaf(fv[j], wv.x, acc[j][0]);
            acc[j][1] = fmaf(fv[j], wv.y, acc[j][1]);
            acc[j][2] = fmaf(fv[j], wv.z, acc[j][2]);
            acc[j][3] = fmaf(fv[j], wv.w, acc[j][3]);
        }
    }

    if (h == 1) {
#pragma unroll
        for (int j = 0; j < 4; j++)
#pragma unroll
            for (int i = 0; i < 4; i++)
                psum[gs * 4 + j][q32 * 4 + i] = acc[j][i];
    }
    __syncthreads();
    if (h == 0) {
#pragma unroll
        for (int j = 0; j < 4; j++) {
#pragma unroll
            for (int i = 0; i < 4; i++) {
                int q = q32 * 4 + i;
                float t = acc[j][i] + psum[gs * 4 + j][q] + bl1[q];
                psum[gs * 4 + j][q] = fmaxf(t, 0.f) * w2[q];
            }
        }
    }
    __syncthreads();

    float b2 = bl2[0];
#pragma unroll
    for (int pass = 0; pass < 2; pass++) {
        int g = (tid >> 5) + pass * 8;
        int l = tid & 31;
        float s = psum[g][l] + psum[g][l + 32] + psum[g][l + 64] + psum[g][l + 96];
        s += __shfl_down(s, 16, 32);
        s += __shfl_down(s, 8, 32);
        s += __shfl_down(s, 4, 32);
        s += __shfl_down(s, 2, 32);
        s += __shfl_down(s, 1, 32);
        if (l == 0 && g0 + g < G) out[g0 + g] = s + b2;
    }
}

extern "C" void kernel_launch(void* const* d_in, const int* in_sizes, int n_in,
                              void* d_out, int out_size, void* d_ws, size_t ws_size,
                              hipStream_t stream) {
    const float* x   = (const float*)d_in[0];
    const int* src   = (const int*)d_in[1];
    const int* dst   = (const int*)d_in[2];
    const int* etype = (const int*)d_in[3];
    const int* uid   = (const int*)d_in[4];
    const int* vid   = (const int*)d_in[5];
    int N = in_sizes[0] / 4;
    int E = in_sizes[1];
    int G = in_sizes[4];
    int K = (N + 255) >> BSH;

    char* wp = (char*)d_ws;
    auto alloc = [&](size_t bytes) {
        char* p = wp;
        wp += (bytes + 255) & ~(size_t)255;
        return p;
    };
    int* row_start   = (int*)alloc((N + 1) * 4);
    int* bucket_cnt  = (int*)alloc(512 * 4);
    int* bucket_base = (int*)alloc(513 * 4);
    int* cursor      = (int*)alloc(512 * 4);
    int* es          = (int*)alloc((size_t)E * 4);
    __half* xhA      = (__half*)alloc((size_t)N * HID * 2);
    __half* xhB      = (__half*)alloc((size_t)N * HID * 2);
    float* C         = (float*)alloc((size_t)N * 128 * 4);
    int* tmp         = (int*)C;   // E ints alias C (consumed by bucketC before C written)

    int ebb = (E + 4095) / 4096;

    // ---- CSR build ----
    zero_kernel<<<2, 256, 0, stream>>>(bucket_cnt, 512);
    bucketA<<<ebb, 256, 0, stream>>>(dst, bucket_cnt, E, K);
    scan_buckets<<<1, 512, 0, stream>>>(bucket_cnt, bucket_base, cursor, K, E);
    bucketB<<<ebb, 256, 0, stream>>>(src, dst, etype, cursor, tmp, E);
    bucketC<<<K, 256, 0, stream>>>(bucket_base, tmp, es, row_start, N, E, K);

    // ---- layer 0 (fp32 x gather, fully fused) ----
    agg0_kernel<<<(N + 127) / 128, 256, 0, stream>>>(
        row_start, es, x,
        (const float*)d_in[6], (const float*)d_in[7],
        (const float*)d_in[8], (const float*)d_in[9],
        C, xhA, N);

    // ---- layers 1-3 (fp16 h gather, fully fused) ----
    int ab = (N + 31) / 32;
    agg_fused<true><<<ab, 256, 0, stream>>>(
        row_start, es, xhA,
        (const float*)d_in[10], (const float*)d_in[11],
        (const float*)d_in[12], (const float*)d_in[13],
        C, xhB, 32, N);
    agg_fused<true><<<ab, 256, 0, stream>>>(
        row_start, es, xhB,
        (const float*)d_in[14], (const float*)d_in[15],
        (const float*)d_in[16], (const float*)d_in[17],
        C, xhA, 64, N);
    agg_fused<false><<<ab, 256, 0, stream>>>(
        row_start, es, xhA,
        (const float*)d_in[18], (const float*)d_in[19],
        (const float*)d_in[20], (const float*)d_in[21],
        C, nullptr, 96, N);

    // ---- final MLP ----
    int gblocks = (G + MP - 1) / MP;
    mlp_kernel<<<gblocks, 256, 0, stream>>>(C, uid, vid,
                                            (const float*)d_in[22], (const float*)d_in[23],
                                            (const float*)d_in[24], (const float*)d_in[25],
                                            (float*)d_out, G);
}